// Round 9
// baseline (504.668 us; speedup 1.0000x reference)
//
#include <hip/hip_runtime.h>
#include <hip/hip_bf16.h>
#include <cstddef>

#define C_ 32
#define D_ 48
#define DP_ 50               // padded act depth: plane 0 = d=-1 zeros, plane 49 = d=48 zeros
#define H_ 64
#define W_ 208
#define WP_ 210              // padded act width: col 0 = w=-1 zeros, col 209 = w=208 zeros
#define HW_ 13312            // H_*W_
#define HS_ 9984             // W_*48, xt h-stride
#define EPS_ 1e-5f

typedef __attribute__((ext_vector_type(8))) short short8;
typedef __attribute__((ext_vector_type(4))) float float4v;
typedef __attribute__((ext_vector_type(16))) float float16v;
typedef __attribute__((ext_vector_type(2))) __fp16 half2v;

// ---------------------------------------------------------------------------
// DPP helpers (VALU-latency cross-lane; invalid lanes keep old = src)
// ---------------------------------------------------------------------------
template<int CTRL>
__device__ __forceinline__ float dppmov(float x) {
    int v = __builtin_bit_cast(int, x);
    return __builtin_bit_cast(float,
        __builtin_amdgcn_update_dpp(v, v, CTRL, 0xf, 0xf, false));
}
template<int CTRL>
__device__ __forceinline__ float dppmax(float m) {
    return fmaxf(m, dppmov<CTRL>(m));
}
__device__ __forceinline__ float rl(float v, int idx) {
    return __builtin_bit_cast(float,
        __builtin_amdgcn_readlane(__builtin_bit_cast(int, v), idx));
}

// One SGA recurrence step, all cross-lane via DPP (lane = d).
__device__ __forceinline__ float sga_step_dpp(float A, float xi,
    float w0, float w1, float w2, float w3, float w4, bool actv, bool ge47)
{
    float up = dppmov<0x138>(A);             // wave_shr:1, lane0 keeps A (d=0 clamp)
    float dn = dppmov<0x130>(A);             // wave_shl:1
    dn = ge47 ? A : dn;                      // d=47 clamp
    float m = actv ? A : -3.4e38f;
    m = dppmax<0x111>(m);
    m = dppmax<0x112>(m);
    m = dppmax<0x114>(m);
    m = dppmax<0x118>(m);
    m = dppmax<0x142>(m);
    m = dppmax<0x143>(m);
    float mall = rl(m, 63);
    return (w0*xi + w1*A) + ((w2*up + w3*dn) + w4*mall);
}

// ---------------------------------------------------------------------------
// Prep: L1-normalize guidance; transpose H-scan weights; repack conv weights;
// zero-fill act's 2 pad cols (per real plane) and 2 pad planes.
// ---------------------------------------------------------------------------
__global__ __launch_bounds__(256) void prep_kernel(
    const float* __restrict__ g, const float* __restrict__ cw,
    float* __restrict__ wn, float* __restrict__ wnT,
    __hip_bfloat16* __restrict__ wrep, unsigned* __restrict__ actu)
{
    int idx = blockIdx.x * 256 + threadIdx.x;
    if (idx < 4 * HW_) {
        int dir = idx / HW_;
        int hw  = idx % HW_;
        const float* gb = g + dir * 5 * HW_ + hw;
        float v0 = gb[0*HW_], v1 = gb[1*HW_], v2 = gb[2*HW_], v3 = gb[3*HW_], v4 = gb[4*HW_];
        float s = fabsf(v0)+fabsf(v1)+fabsf(v2)+fabsf(v3)+fabsf(v4);
        float inv = 1.0f / fmaxf(s, 1e-12f);
        v0 *= inv; v1 *= inv; v2 *= inv; v3 *= inv; v4 *= inv;
        float* ob = wn + dir * 5 * HW_ + hw;
        ob[0*HW_] = v0; ob[1*HW_] = v1; ob[2*HW_] = v2; ob[3*HW_] = v3; ob[4*HW_] = v4;
        if (dir >= 2) {   // H-scan dirs: also write [dd][i][w][h]
            int hq = hw / W_, wq = hw % W_;
            float* oT = wnT + ((size_t)((dir-2)*5)*W_ + wq)*H_ + hq;
            oT[0]       = v0; oT[1*HW_] = v1; oT[2*HW_] = v2;
            oT[3*HW_]   = v3; oT[4*HW_] = v4;   // i-stride = W_*H_ = HW_
        }
    } else if (idx < 4 * HW_ + 27648) {
        int j = idx - 4 * HW_;
        int e    = j & 7;
        int lane = (j >> 3) & 63;
        int q    = j >> 9;            // 0..53
        int cih  = q & 1;
        int tap  = q >> 1;
        int co = lane & 31;
        int ci = cih * 16 + (lane >> 5) * 8 + e;
        wrep[j] = __float2bfloat16(cw[(co * C_ + ci) * 27 + tap]);
    } else if (idx < 4 * HW_ + 27648 + 98304) {
        int j2 = idx - (4 * HW_ + 27648);   // w-pad cols of the 48 real planes
        int hd  = j2 >> 5;                  // h*48 + dd, in [0,3072)
        int r   = j2 & 31;
        int col = (r >> 4) ? 209 : 0;
        int cu  = r & 15;
        int h = hd / 48, dd = hd % 48;
        actu[(((size_t)h * DP_ + dd + 1) * WP_ + col) * 16 + cu] = 0u;
    } else {
        int j3 = idx - (4 * HW_ + 27648 + 98304);   // [0, 430080): 2 d-pad planes
        int pl   = j3 >= 215040;            // 215040 = 64*210*16
        int r3   = pl ? j3 - 215040 : j3;
        int h    = r3 / 3360;               // 3360 = 210*16
        int rest = r3 % 3360;
        int dpad = pl ? (DP_ - 1) : 0;
        actu[((size_t)h * DP_ + dpad) * WP_ * 16 + rest] = 0u;
    }
}

// ---------------------------------------------------------------------------
// t0: transpose x [c][d][h][w] fp32 -> xt [c][h][w][d] bf16 (lives in d_out)
// ---------------------------------------------------------------------------
__global__ __launch_bounds__(256) void t0_kernel(
    const float* __restrict__ x, __hip_bfloat16* __restrict__ xt)
{
    __shared__ float t[48 * 257];
    int tid = threadIdx.x;
    int c  = blockIdx.x / 52;
    int q0 = (blockIdx.x % 52) * 256;
    #pragma unroll
    for (int dd = 0; dd < 48; ++dd)
        t[dd * 257 + tid] = x[((size_t)c * 48 + dd) * HW_ + q0 + tid];
    __syncthreads();
    unsigned* xtu = (unsigned*)xt;
    #pragma unroll
    for (int k = 0; k < 24; ++k) {
        int f = tid + 256 * k;              // < 6144 bf16-pairs
        int d2 = f % 24, hwl = f / 24;
        union { unsigned u; __hip_bfloat16 hh[2]; } pk;
        pk.hh[0] = __float2bfloat16(t[(2 * d2) * 257 + hwl]);
        pk.hh[1] = __float2bfloat16(t[(2 * d2 + 1) * 257 + hwl]);
        xtu[(((size_t)c * HW_ + q0 + hwl) * 48 + 2 * d2) >> 1] = pk.u;
    }
}

// ---------------------------------------------------------------------------
// Horizontal scans, fwd/rev SPLIT: block = 128 threads = 2 waves {fwd, rev}
// for one (c,h) row. Each wave runs a 208-step chain; keeps its own
// merge-half (104 values) fp16-packed in 52 VGPRs and writes the OTHER
// half to LDS. One barrier; each wave merges 104 positions (max(d1,d2)).
// LDS 19,968 B -> 8 blocks/CU -> 4 waves/SIMD (2x the fused version).
// ---------------------------------------------------------------------------
__global__ __launch_bounds__(128, 4) void sga_w_kernel(
    const __hip_bfloat16* __restrict__ xt, const float* __restrict__ wn,
    __hip_bfloat16* __restrict__ d12)
{
    __shared__ __fp16 sO[2][104][48];   // [0]: d1 for p>=104 (by fwd); [1]: d2 for p<104 (by rev)

    int lane = threadIdx.x & 63;
    int dir  = threadIdx.x >> 6;          // 0 = fwd (d1), 1 = rev (d2)
    int wid  = blockIdx.x;                // 0..2047
    int c = wid >> 6, h = wid & 63;
    int d = lane < 48 ? lane : 47;
    bool actv = lane < 48, ge47 = lane >= 47;
    const __hip_bfloat16* xp = xt + ((size_t)c * HW_ + h * W_) * 48 + d;   // + p*48
    const float* wb = wn + (size_t)dir * 5 * HW_ + h * W_;                 // + i*HW_ + p
    int il = lane >> 3, jl = lane & 7;    // weight gather: lane il*8+jl -> dir il, offset jl
    bool wact = il < 5;

    unsigned selfp[52];                   // own half, fp16-packed (even=lo, odd=hi)
    float xb[3][8];
    float wAr[3];

    if (dir == 0) {
        // ---- forward scan p = 0..207; keep p<104 in regs, p>=104 -> LDS ----
        #pragma unroll
        for (int j = 0; j < 8; ++j) {
            xb[0][j] = __bfloat162float(xp[(size_t)j * 48]);
            xb[1][j] = __bfloat162float(xp[(size_t)(8 + j) * 48]);
        }
        wAr[0] = wact ? wb[il * HW_ + jl] : 0.0f;
        wAr[1] = wact ? wb[il * HW_ + 8 + jl] : 0.0f;
        float A = xb[0][0];
        float Aev = 0.0f;
        #pragma unroll
        for (int cc = 0; cc < 26; ++cc) {
            const int buf = cc % 3;
            if (cc < 24) {                // prefetch 2 chunks ahead
                const int nb = (cc + 2) % 3;
                #pragma unroll
                for (int j = 0; j < 8; ++j)
                    xb[nb][j] = __bfloat162float(xp[(size_t)((cc + 2) * 8 + j) * 48]);
                wAr[nb] = wact ? wb[il * HW_ + (cc + 2) * 8 + jl] : 0.0f;
            }
            #pragma unroll
            for (int j = 0; j < 8; ++j) {
                A = sga_step_dpp(A, xb[buf][j], rl(wAr[buf], j), rl(wAr[buf], 8 + j),
                                 rl(wAr[buf], 16 + j), rl(wAr[buf], 24 + j),
                                 rl(wAr[buf], 32 + j), actv, ge47);
                const int p = cc * 8 + j;
                if (p < 104) {
                    if (j & 1) {
                        half2v pk2 = __builtin_amdgcn_cvt_pkrtz(Aev, A);
                        selfp[p >> 1] = __builtin_bit_cast(unsigned, pk2);
                    } else {
                        Aev = A;
                    }
                } else {
                    if (actv) sO[0][p - 104][d] = (__fp16)A;
                }
            }
        }
    } else {
        // ---- reverse scan p = 207..0; keep p>=104 in regs, p<104 -> LDS ----
        #pragma unroll
        for (int j = 0; j < 8; ++j) {
            xb[0][j] = __bfloat162float(xp[(size_t)(200 + j) * 48]);
            xb[1][j] = __bfloat162float(xp[(size_t)(192 + j) * 48]);
        }
        wAr[0] = wact ? wb[il * HW_ + 200 + jl] : 0.0f;
        wAr[1] = wact ? wb[il * HW_ + 192 + jl] : 0.0f;
        float A = xb[0][7];
        float Aod = 0.0f;
        #pragma unroll
        for (int cc2 = 0; cc2 < 26; ++cc2) {
            const int cc = 25 - cc2;
            const int buf = cc2 % 3;
            if (cc2 < 24) {               // prefetch 2 chunks ahead (descending)
                const int nb = (cc2 + 2) % 3;
                #pragma unroll
                for (int j = 0; j < 8; ++j)
                    xb[nb][j] = __bfloat162float(xp[(size_t)((cc - 2) * 8 + j) * 48]);
                wAr[nb] = wact ? wb[il * HW_ + (cc - 2) * 8 + jl] : 0.0f;
            }
            #pragma unroll
            for (int j = 7; j >= 0; --j) {
                A = sga_step_dpp(A, xb[buf][j], rl(wAr[buf], j), rl(wAr[buf], 8 + j),
                                 rl(wAr[buf], 16 + j), rl(wAr[buf], 24 + j),
                                 rl(wAr[buf], 32 + j), actv, ge47);
                const int p = cc * 8 + j;
                if (p >= 104) {
                    const int q = p - 104;
                    if (j & 1) {
                        Aod = A;          // odd visited first
                    } else {
                        half2v pk2 = __builtin_amdgcn_cvt_pkrtz(A, Aod);
                        selfp[q >> 1] = __builtin_bit_cast(unsigned, pk2);
                    }
                } else {
                    if (actv) sO[1][p][d] = (__fp16)A;
                }
            }
        }
    }

    __syncthreads();

    // ---- merge own half with the other direction's LDS half ----
    __hip_bfloat16* dp = d12 + ((size_t)c * HW_ + h * W_) * 48 + d;
    if (actv) {
        if (dir == 0) {
            #pragma unroll
            for (int p = 0; p < 104; ++p) {
                half2v hp = __builtin_bit_cast(half2v, selfp[p >> 1]);
                float mine = (float)((p & 1) ? hp[1] : hp[0]);
                float oth  = (float)sO[1][p][d];
                dp[(size_t)p * 48] = __float2bfloat16(fmaxf(mine, oth));
            }
        } else {
            #pragma unroll
            for (int q = 0; q < 104; ++q) {
                half2v hp = __builtin_bit_cast(half2v, selfp[q >> 1]);
                float mine = (float)((q & 1) ? hp[1] : hp[0]);
                float oth  = (float)sO[0][q][d];
                dp[(size_t)(104 + q) * 48] = __float2bfloat16(fmaxf(mine, oth));
            }
        }
    }
}

// ---------------------------------------------------------------------------
// Vertical scans, fwd/rev SPLIT: 2 columns per block, 4 waves =
// (col x {fwd,rev}); results meet in LDS; merge phase is 32 independent rows
// per wave (max(d3,d4,d12) + BN1 + ReLU).
// ---------------------------------------------------------------------------
__global__ __launch_bounds__(256, 6) void sga_h_kernel(
    const __hip_bfloat16* __restrict__ xt, const float* __restrict__ wnT,
    __hip_bfloat16* __restrict__ d12,
    const float* __restrict__ g1, const float* __restrict__ b1,
    const float* __restrict__ m1, const float* __restrict__ v1)
{
    __shared__ __fp16 sA[2][2][64][48];   // [colb][dir][h][d]

    int lane = threadIdx.x & 63;
    int widb = threadIdx.x >> 6;          // 0..3
    int colb = widb >> 1;                 // column within block
    int dir  = widb & 1;                  // 0 = fwd (d3), 1 = rev (d4)
    int gcol = blockIdx.x * 2 + colb;     // 0..6655
    int c = gcol / W_, w = gcol % W_;
    int d = lane < 48 ? lane : 47;
    bool actv = lane < 48, ge47 = lane >= 47;
    const __hip_bfloat16* xp = xt + ((size_t)c * HW_ + w) * 48 + d;   // + h*HS_
    const float* wb = wnT + ((size_t)(dir * 5) * W_ + w) * H_;        // + i*HW_ + h
    int il = lane >> 3, jl = lane & 7;    // weight gather: lane il*8+jl -> dir il, offset jl
    bool wact = il < 5;

    float xb[3][8];
    float wAr[3];

    if (dir == 0) {
        // ---- forward scan h = 0..63 ----
        #pragma unroll
        for (int j = 0; j < 8; ++j) {
            xb[0][j] = __bfloat162float(xp[(size_t)j * HS_]);
            xb[1][j] = __bfloat162float(xp[(size_t)(8 + j) * HS_]);
        }
        wAr[0] = wact ? wb[il * HW_ + jl] : 0.0f;
        wAr[1] = wact ? wb[il * HW_ + 8 + jl] : 0.0f;
        float A = xb[0][0];
        #pragma unroll
        for (int cc = 0; cc < 8; ++cc) {
            const int buf = cc % 3;
            if (cc < 6) {                 // prefetch 2 chunks ahead
                const int nb = (cc + 2) % 3;
                #pragma unroll
                for (int j = 0; j < 8; ++j)
                    xb[nb][j] = __bfloat162float(xp[(size_t)((cc + 2) * 8 + j) * HS_]);
                wAr[nb] = wact ? wb[il * HW_ + (cc + 2) * 8 + jl] : 0.0f;
            }
            #pragma unroll
            for (int j = 0; j < 8; ++j) {
                A = sga_step_dpp(A, xb[buf][j], rl(wAr[buf], j), rl(wAr[buf], 8 + j),
                                 rl(wAr[buf], 16 + j), rl(wAr[buf], 24 + j),
                                 rl(wAr[buf], 32 + j), actv, ge47);
                if (actv) sA[colb][0][cc * 8 + j][d] = (__fp16)A;
            }
        }
    } else {
        // ---- reverse scan h = 63..0 ----
        #pragma unroll
        for (int j = 0; j < 8; ++j) {
            xb[0][j] = __bfloat162float(xp[(size_t)(56 + j) * HS_]);
            xb[1][j] = __bfloat162float(xp[(size_t)(48 + j) * HS_]);
        }
        wAr[0] = wact ? wb[il * HW_ + 56 + jl] : 0.0f;
        wAr[1] = wact ? wb[il * HW_ + 48 + jl] : 0.0f;
        float A = xb[0][7];
        #pragma unroll
        for (int cc2 = 0; cc2 < 8; ++cc2) {
            const int cc = 7 - cc2;       // chunk base descending
            const int buf = cc2 % 3;
            if (cc2 < 6) {
                const int nb = (cc2 + 2) % 3;
                #pragma unroll
                for (int j = 0; j < 8; ++j)
                    xb[nb][j] = __bfloat162float(xp[(size_t)((cc - 2) * 8 + j) * HS_]);
                wAr[nb] = wact ? wb[il * HW_ + (cc - 2) * 8 + jl] : 0.0f;
            }
            #pragma unroll
            for (int j = 7; j >= 0; --j) {
                A = sga_step_dpp(A, xb[buf][j], rl(wAr[buf], j), rl(wAr[buf], 8 + j),
                                 rl(wAr[buf], 16 + j), rl(wAr[buf], 24 + j),
                                 rl(wAr[buf], 32 + j), actv, ge47);
                if (actv) sA[colb][1][cc * 8 + j][d] = (__fp16)A;
            }
        }
    }

    __syncthreads();

    // ---- merge: this wave handles its column, h in [dir*32, dir*32+32) ----
    float s1 = g1[c] * rsqrtf(v1[c] + EPS_);
    float o1 = b1[c] - m1[c] * s1;
    __hip_bfloat16* dp = d12 + ((size_t)c * HW_ + w) * 48 + d;
    #pragma unroll
    for (int t = 0; t < 32; ++t) {
        int h = dir * 32 + t;
        float dv = __bfloat162float(dp[(size_t)h * HS_]);
        float d3 = (float)sA[colb][0][h][d];
        float d4 = (float)sA[colb][1][h][d];
        float comb = fmaxf(fmaxf(d3, d4), dv);
        if (actv)
            dp[(size_t)h * HS_] = __float2bfloat16(fmaxf(comb * s1 + o1, 0.0f));
    }
}

// ---------------------------------------------------------------------------
// trans: st bf16 [c][h][w][d] -> act bf16 [h][DP][WP][c], d,w shifted +1
// ---------------------------------------------------------------------------
__global__ __launch_bounds__(256) void trans_kernel(
    const __hip_bfloat16* __restrict__ st, __hip_bfloat16* __restrict__ act)
{
    __shared__ float t[8 * 1571];   // addr = wl*1571 + c*49 + d
    int tid = threadIdx.x;
    int h  = blockIdx.x / 26;
    int w0 = (blockIdx.x % 26) * 8;
    const unsigned* stu = (const unsigned*)st;
    #pragma unroll
    for (int k = 0; k < 24; ++k) {
        int f = tid + 256 * k;              // < 6144
        int d2 = f % 24, wl = (f / 24) % 8, c = f / 192;
        unsigned u = stu[(((size_t)c * HW_ + h * W_ + w0 + wl) * 48 + 2 * d2) >> 1];
        const __hip_bfloat16* bp = (const __hip_bfloat16*)&u;
        t[wl * 1571 + c * 49 + 2 * d2]     = __bfloat162float(bp[0]);
        t[wl * 1571 + c * 49 + 2 * d2 + 1] = __bfloat162float(bp[1]);
    }
    __syncthreads();
    unsigned* actu = (unsigned*)act;
    #pragma unroll
    for (int k = 0; k < 24; ++k) {
        int f = tid + 256 * k;              // < 6144
        int cp = f % 16, wl = (f / 16) % 8, d = f / 128;
        union { unsigned u; __hip_bfloat16 hh[2]; } pk;
        pk.hh[0] = __float2bfloat16(t[wl * 1571 + (2 * cp) * 49 + d]);
        pk.hh[1] = __float2bfloat16(t[wl * 1571 + (2 * cp + 1) * 49 + d]);
        actu[(((size_t)h * DP_ + d + 1) * WP_ + w0 + wl + 1) * 16 + cp] = pk.u;
    }
}

// ---------------------------------------------------------------------------
// Conv 3x3x3, block-cooperative LDS-staged implicit GEMM (MFMA 32x32x16).
// Block = 4 waves = 32co x 32w x 8d. Per kh-row: stage act brick
// [10 dp][34 wl][32 c] (c padded to 40 in LDS for bank spread) once, then
// each wave (2 d-planes, 32 AGPR acc) streams ds_read_b128 + MFMA.
// act is d- AND w-zero-padded -> no boundary logic anywhere.
// ---------------------------------------------------------------------------
__global__ __launch_bounds__(256, 4) void conv_kernel(
    const __hip_bfloat16* __restrict__ act,   // [H][DP][WP][C]
    const short8* __restrict__ wrep,          // [27][2][64] short8
    const float* __restrict__ x,
    const float* __restrict__ g2, const float* __restrict__ b2,
    const float* __restrict__ m2, const float* __restrict__ v2,
    float* __restrict__ out)
{
    __shared__ __hip_bfloat16 sAct[10 * 34 * 40];

    int tid  = threadIdx.x;
    int lane = tid & 63;
    int v    = tid >> 6;                 // wave 0..3
    int bid  = blockIdx.x;
    int wt   = bid % 7;
    int t    = bid / 7;
    int h    = t & 63;
    int d0b  = (t >> 6) * 8;             // block d-base: 0,8,...,40
    int w0   = wt * 32;
    int n    = lane & 31;
    int half = lane >> 5;

    float16v acc0 = (float16v)(0.0f);
    float16v acc1 = (float16v)(0.0f);

    const short8* ap8 = (const short8*)act;

    #pragma unroll
    for (int kh = 0; kh < 3; ++kh) {
        int hh = h + kh - 1;
        if (hh < 0 || hh >= H_) continue;          // block-uniform
        __syncthreads();                           // prev-iter reads done
        #pragma unroll
        for (int k = 0; k < 6; ++k) {
            int i = tid + 256 * k;                 // 1360 chunks of 16B
            if (i < 1360) {
                int dp = i / 136;
                int r  = i - dp * 136;
                int wl = r >> 2, q = r & 3;
                int wc = w0 + wl; wc = wc < 209 ? wc : 209;   // clamp to zero col
                short8 vd = ap8[(((size_t)hh * DP_ + d0b + dp) * WP_ + wc) * 4 + q];
                *(short8*)&sAct[(dp * 34 + wl) * 40 + q * 8] = vd;
            }
        }
        __syncthreads();
        #pragma unroll
        for (int kw = 0; kw < 3; ++kw) {
            #pragma unroll
            for (int cih = 0; cih < 2; ++cih) {
                short8 af[3];
                #pragma unroll
                for (int kd = 0; kd < 3; ++kd)
                    af[kd] = wrep[(((kd*3 + kh)*3 + kw)*2 + cih)*64 + lane];
                short8 bf[4];
                #pragma unroll
                for (int p = 0; p < 4; ++p)
                    bf[p] = *(const short8*)
                        &sAct[((2*v + p) * 34 + kw + n) * 40 + cih * 16 + half * 8];
                #pragma unroll
                for (int kd = 0; kd < 3; ++kd) {
                    acc0 = __builtin_amdgcn_mfma_f32_32x32x16_bf16(af[kd], bf[kd],   acc0, 0, 0, 0);
                    acc1 = __builtin_amdgcn_mfma_f32_32x32x16_bf16(af[kd], bf[kd+1], acc1, 0, 0, 0);
                }
            }
        }
    }

    int d0 = d0b + 2 * v;
    int wl = w0 + n;
    bool wvalid = wl < W_;
    int coh = 4 * half;
    #pragma unroll
    for (int r = 0; r < 16; ++r) {
        int co = (r & 3) + 8 * (r >> 2) + coh;
        float s2 = g2[co] * rsqrtf(v2[co] + EPS_);
        float o2 = b2[co] - m2[co] * s2;
        size_t idx0 = ((size_t)(co * D_ + d0) * H_ + h) * W_ + wl;
        if (wvalid) {
            out[idx0]       = fmaxf(acc0[r] * s2 + o2 + x[idx0],       0.0f);
            out[idx0 + HW_] = fmaxf(acc1[r] * s2 + o2 + x[idx0 + HW_], 0.0f);
        }
    }
}

// ---------------------------------------------------------------------------
extern "C" void kernel_launch(void* const* d_in, const int* in_sizes, int n_in,
                              void* d_out, int out_size, void* d_ws, size_t ws_size,
                              hipStream_t stream)
{
    const float* x    = (const float*)d_in[0];
    const float* g    = (const float*)d_in[1];
    const float* cw   = (const float*)d_in[2];
    const float* bn1g = (const float*)d_in[3];
    const float* bn1b = (const float*)d_in[4];
    const float* bn1m = (const float*)d_in[5];
    const float* bn1v = (const float*)d_in[6];
    const float* bn2g = (const float*)d_in[7];
    const float* bn2b = (const float*)d_in[8];
    const float* bn2m = (const float*)d_in[9];
    const float* bn2v = (const float*)d_in[10];
    float* out = (float*)d_out;

    char* ws = (char*)d_ws;
    float* wn  = (float*)ws;                                   // 1,064,960 B
    float* wnT = (float*)(ws + 1064960);                       //   532,480 B
    __hip_bfloat16* wrep = (__hip_bfloat16*)(ws + 1597440);    //    55,296 B
    __hip_bfloat16* d12t = (__hip_bfloat16*)(ws + 1652736);    // 40,894,464 B
    __hip_bfloat16* act  = (__hip_bfloat16*)(ws + 42547200);   // 43,008,000 B (d+w padded)
    __hip_bfloat16* xt = (__hip_bfloat16*)out;  // d_out as bf16 xt scratch

    prep_kernel<<<2380, 256, 0, stream>>>(g, cw, wn, wnT, wrep, (unsigned*)act);
    t0_kernel<<<1664, 256, 0, stream>>>(x, xt);
    sga_w_kernel<<<2048, 128, 0, stream>>>(xt, wn, d12t);
    sga_h_kernel<<<3328, 256, 0, stream>>>(xt, wnT, d12t, bn1g, bn1b, bn1m, bn1v);
    trans_kernel<<<1664, 256, 0, stream>>>(d12t, act);
    conv_kernel<<<2688, 256, 0, stream>>>(act, (const short8*)wrep, x,
                                          bn2g, bn2b, bn2m, bn2v, out);
}

// Round 10
// 411.916 us; speedup vs baseline: 1.2252x; 1.2252x over previous
//
#include <hip/hip_runtime.h>
#include <hip/hip_bf16.h>
#include <cstddef>

#define C_ 32
#define D_ 48
#define DP_ 50               // padded act depth: plane 0 = d=-1 zeros, plane 49 = d=48 zeros
#define H_ 64
#define W_ 208
#define WP_ 210              // padded act width: col 0 = w=-1 zeros, col 209 = w=208 zeros
#define HW_ 13312            // H_*W_
#define HS_ 9984             // W_*48, xt h-stride
#define EPS_ 1e-5f

typedef __attribute__((ext_vector_type(8))) short short8;
typedef __attribute__((ext_vector_type(4))) float float4v;
typedef __attribute__((ext_vector_type(16))) float float16v;
typedef __attribute__((ext_vector_type(2))) __fp16 half2v;

// ---------------------------------------------------------------------------
// DPP helpers (VALU-latency cross-lane; invalid lanes keep old = src)
// ---------------------------------------------------------------------------
template<int CTRL>
__device__ __forceinline__ float dppmov(float x) {
    int v = __builtin_bit_cast(int, x);
    return __builtin_bit_cast(float,
        __builtin_amdgcn_update_dpp(v, v, CTRL, 0xf, 0xf, false));
}
template<int CTRL>
__device__ __forceinline__ float dppmax(float m) {
    return fmaxf(m, dppmov<CTRL>(m));
}
__device__ __forceinline__ float rl(float v, int idx) {
    return __builtin_bit_cast(float,
        __builtin_amdgcn_readlane(__builtin_bit_cast(int, v), idx));
}

// One SGA recurrence step, all cross-lane via DPP (lane = d).
__device__ __forceinline__ float sga_step_dpp(float A, float xi,
    float w0, float w1, float w2, float w3, float w4, bool actv, bool ge47)
{
    float up = dppmov<0x138>(A);             // wave_shr:1, lane0 keeps A (d=0 clamp)
    float dn = dppmov<0x130>(A);             // wave_shl:1
    dn = ge47 ? A : dn;                      // d=47 clamp
    float m = actv ? A : -3.4e38f;
    m = dppmax<0x111>(m);
    m = dppmax<0x112>(m);
    m = dppmax<0x114>(m);
    m = dppmax<0x118>(m);
    m = dppmax<0x142>(m);
    m = dppmax<0x143>(m);
    float mall = rl(m, 63);
    return (w0*xi + w1*A) + ((w2*up + w3*dn) + w4*mall);
}

// ---------------------------------------------------------------------------
// Prep: L1-normalize guidance; transpose H-scan weights; repack conv weights;
// zero-fill act's 2 pad cols (per real plane) and 2 pad planes.
// ---------------------------------------------------------------------------
__global__ __launch_bounds__(256) void prep_kernel(
    const float* __restrict__ g, const float* __restrict__ cw,
    float* __restrict__ wn, float* __restrict__ wnT,
    __hip_bfloat16* __restrict__ wrep, unsigned* __restrict__ actu)
{
    int idx = blockIdx.x * 256 + threadIdx.x;
    if (idx < 4 * HW_) {
        int dir = idx / HW_;
        int hw  = idx % HW_;
        const float* gb = g + dir * 5 * HW_ + hw;
        float v0 = gb[0*HW_], v1 = gb[1*HW_], v2 = gb[2*HW_], v3 = gb[3*HW_], v4 = gb[4*HW_];
        float s = fabsf(v0)+fabsf(v1)+fabsf(v2)+fabsf(v3)+fabsf(v4);
        float inv = 1.0f / fmaxf(s, 1e-12f);
        v0 *= inv; v1 *= inv; v2 *= inv; v3 *= inv; v4 *= inv;
        float* ob = wn + dir * 5 * HW_ + hw;
        ob[0*HW_] = v0; ob[1*HW_] = v1; ob[2*HW_] = v2; ob[3*HW_] = v3; ob[4*HW_] = v4;
        if (dir >= 2) {   // H-scan dirs: also write [dd][i][w][h]
            int hq = hw / W_, wq = hw % W_;
            float* oT = wnT + ((size_t)((dir-2)*5)*W_ + wq)*H_ + hq;
            oT[0]       = v0; oT[1*HW_] = v1; oT[2*HW_] = v2;
            oT[3*HW_]   = v3; oT[4*HW_] = v4;   // i-stride = W_*H_ = HW_
        }
    } else if (idx < 4 * HW_ + 27648) {
        int j = idx - 4 * HW_;
        int e    = j & 7;
        int lane = (j >> 3) & 63;
        int q    = j >> 9;            // 0..53
        int cih  = q & 1;
        int tap  = q >> 1;
        int co = lane & 31;
        int ci = cih * 16 + (lane >> 5) * 8 + e;
        wrep[j] = __float2bfloat16(cw[(co * C_ + ci) * 27 + tap]);
    } else if (idx < 4 * HW_ + 27648 + 98304) {
        int j2 = idx - (4 * HW_ + 27648);   // w-pad cols of the 48 real planes
        int hd  = j2 >> 5;                  // h*48 + dd, in [0,3072)
        int r   = j2 & 31;
        int col = (r >> 4) ? 209 : 0;
        int cu  = r & 15;
        int h = hd / 48, dd = hd % 48;
        actu[(((size_t)h * DP_ + dd + 1) * WP_ + col) * 16 + cu] = 0u;
    } else {
        int j3 = idx - (4 * HW_ + 27648 + 98304);   // [0, 430080): 2 d-pad planes
        int pl   = j3 >= 215040;            // 215040 = 64*210*16
        int r3   = pl ? j3 - 215040 : j3;
        int h    = r3 / 3360;               // 3360 = 210*16
        int rest = r3 % 3360;
        int dpad = pl ? (DP_ - 1) : 0;
        actu[((size_t)h * DP_ + dpad) * WP_ * 16 + rest] = 0u;
    }
}

// ---------------------------------------------------------------------------
// t0: transpose x [c][d][h][w] fp32 -> xt [c][h][w][d] bf16 (lives in d_out)
// ---------------------------------------------------------------------------
__global__ __launch_bounds__(256) void t0_kernel(
    const float* __restrict__ x, __hip_bfloat16* __restrict__ xt)
{
    __shared__ float t[48 * 257];
    int tid = threadIdx.x;
    int c  = blockIdx.x / 52;
    int q0 = (blockIdx.x % 52) * 256;
    #pragma unroll
    for (int dd = 0; dd < 48; ++dd)
        t[dd * 257 + tid] = x[((size_t)c * 48 + dd) * HW_ + q0 + tid];
    __syncthreads();
    unsigned* xtu = (unsigned*)xt;
    #pragma unroll
    for (int k = 0; k < 24; ++k) {
        int f = tid + 256 * k;              // < 6144 bf16-pairs
        int d2 = f % 24, hwl = f / 24;
        union { unsigned u; __hip_bfloat16 hh[2]; } pk;
        pk.hh[0] = __float2bfloat16(t[(2 * d2) * 257 + hwl]);
        pk.hh[1] = __float2bfloat16(t[(2 * d2 + 1) * 257 + hwl]);
        xtu[(((size_t)c * HW_ + q0 + hwl) * 48 + 2 * d2) >> 1] = pk.u;
    }
}

// ---------------------------------------------------------------------------
// Horizontal scans, fwd/rev SPLIT, all-LDS variant (no packed-reg array ->
// no scratch spill). Block = 256 threads = 4 waves = 2 rows x {fwd,rev}.
// Each wave runs a 208-step half-chain writing every result to LDS fp16;
// one barrier; wave (row,dir) merges p in [dir*104, dir*104+104) with a
// pure max -> d12 written exactly once. LDS 39,936 B -> 4 blocks/CU =
// 16 waves/CU (~2.8x the fused version's residency), regs ~50.
// ---------------------------------------------------------------------------
__global__ __launch_bounds__(256, 4) void sga_w_kernel(
    const __hip_bfloat16* __restrict__ xt, const float* __restrict__ wn,
    __hip_bfloat16* __restrict__ d12)
{
    __shared__ __fp16 sO[2][2][208][48];   // [rowb][dir][p][d]

    int lane = threadIdx.x & 63;
    int widb = threadIdx.x >> 6;          // 0..3
    int rowb = widb >> 1;                 // row within block
    int dir  = widb & 1;                  // 0 = fwd (d1), 1 = rev (d2)
    int grow = blockIdx.x * 2 + rowb;     // 0..2047
    int c = grow >> 6, h = grow & 63;
    int d = lane < 48 ? lane : 47;
    bool actv = lane < 48, ge47 = lane >= 47;
    const __hip_bfloat16* xp = xt + ((size_t)c * HW_ + h * W_) * 48 + d;   // + p*48
    const float* wb = wn + (size_t)dir * 5 * HW_ + h * W_;                 // + i*HW_ + p
    int il = lane >> 3, jl = lane & 7;    // weight gather: lane il*8+jl -> dir il, offset jl
    bool wact = il < 5;

    float xb[3][8];
    float wAr[3];

    if (dir == 0) {
        // ---- forward scan p = 0..207 ----
        #pragma unroll
        for (int j = 0; j < 8; ++j) {
            xb[0][j] = __bfloat162float(xp[(size_t)j * 48]);
            xb[1][j] = __bfloat162float(xp[(size_t)(8 + j) * 48]);
        }
        wAr[0] = wact ? wb[il * HW_ + jl] : 0.0f;
        wAr[1] = wact ? wb[il * HW_ + 8 + jl] : 0.0f;
        float A = xb[0][0];
        #pragma unroll
        for (int cc = 0; cc < 26; ++cc) {
            const int buf = cc % 3;
            if (cc < 24) {                // prefetch 2 chunks ahead
                const int nb = (cc + 2) % 3;
                #pragma unroll
                for (int j = 0; j < 8; ++j)
                    xb[nb][j] = __bfloat162float(xp[(size_t)((cc + 2) * 8 + j) * 48]);
                wAr[nb] = wact ? wb[il * HW_ + (cc + 2) * 8 + jl] : 0.0f;
            }
            #pragma unroll
            for (int j = 0; j < 8; ++j) {
                A = sga_step_dpp(A, xb[buf][j], rl(wAr[buf], j), rl(wAr[buf], 8 + j),
                                 rl(wAr[buf], 16 + j), rl(wAr[buf], 24 + j),
                                 rl(wAr[buf], 32 + j), actv, ge47);
                if (actv) sO[rowb][0][cc * 8 + j][d] = (__fp16)A;
            }
        }
    } else {
        // ---- reverse scan p = 207..0 ----
        #pragma unroll
        for (int j = 0; j < 8; ++j) {
            xb[0][j] = __bfloat162float(xp[(size_t)(200 + j) * 48]);
            xb[1][j] = __bfloat162float(xp[(size_t)(192 + j) * 48]);
        }
        wAr[0] = wact ? wb[il * HW_ + 200 + jl] : 0.0f;
        wAr[1] = wact ? wb[il * HW_ + 192 + jl] : 0.0f;
        float A = xb[0][7];
        #pragma unroll
        for (int cc2 = 0; cc2 < 26; ++cc2) {
            const int cc = 25 - cc2;
            const int buf = cc2 % 3;
            if (cc2 < 24) {               // prefetch 2 chunks ahead (descending)
                const int nb = (cc2 + 2) % 3;
                #pragma unroll
                for (int j = 0; j < 8; ++j)
                    xb[nb][j] = __bfloat162float(xp[(size_t)((cc - 2) * 8 + j) * 48]);
                wAr[nb] = wact ? wb[il * HW_ + (cc - 2) * 8 + jl] : 0.0f;
            }
            #pragma unroll
            for (int j = 7; j >= 0; --j) {
                A = sga_step_dpp(A, xb[buf][j], rl(wAr[buf], j), rl(wAr[buf], 8 + j),
                                 rl(wAr[buf], 16 + j), rl(wAr[buf], 24 + j),
                                 rl(wAr[buf], 32 + j), actv, ge47);
                if (actv) sO[rowb][1][cc * 8 + j][d] = (__fp16)A;
            }
        }
    }

    __syncthreads();

    // ---- merge: wave (rowb,dir) handles p in [dir*104, dir*104+104) ----
    __hip_bfloat16* dp = d12 + ((size_t)c * HW_ + h * W_) * 48 + d;
    if (actv) {
        const int p0 = dir * 104;
        #pragma unroll
        for (int t = 0; t < 104; ++t) {
            int p = p0 + t;
            float d1 = (float)sO[rowb][0][p][d];
            float d2 = (float)sO[rowb][1][p][d];
            dp[(size_t)p * 48] = __float2bfloat16(fmaxf(d1, d2));
        }
    }
}

// ---------------------------------------------------------------------------
// Vertical scans, fwd/rev SPLIT: 2 columns per block, 4 waves =
// (col x {fwd,rev}); results meet in LDS; merge phase is 32 independent rows
// per wave (max(d3,d4,d12) + BN1 + ReLU).
// ---------------------------------------------------------------------------
__global__ __launch_bounds__(256, 6) void sga_h_kernel(
    const __hip_bfloat16* __restrict__ xt, const float* __restrict__ wnT,
    __hip_bfloat16* __restrict__ d12,
    const float* __restrict__ g1, const float* __restrict__ b1,
    const float* __restrict__ m1, const float* __restrict__ v1)
{
    __shared__ __fp16 sA[2][2][64][48];   // [colb][dir][h][d]

    int lane = threadIdx.x & 63;
    int widb = threadIdx.x >> 6;          // 0..3
    int colb = widb >> 1;                 // column within block
    int dir  = widb & 1;                  // 0 = fwd (d3), 1 = rev (d4)
    int gcol = blockIdx.x * 2 + colb;     // 0..6655
    int c = gcol / W_, w = gcol % W_;
    int d = lane < 48 ? lane : 47;
    bool actv = lane < 48, ge47 = lane >= 47;
    const __hip_bfloat16* xp = xt + ((size_t)c * HW_ + w) * 48 + d;   // + h*HS_
    const float* wb = wnT + ((size_t)(dir * 5) * W_ + w) * H_;        // + i*HW_ + h
    int il = lane >> 3, jl = lane & 7;    // weight gather: lane il*8+jl -> dir il, offset jl
    bool wact = il < 5;

    float xb[3][8];
    float wAr[3];

    if (dir == 0) {
        // ---- forward scan h = 0..63 ----
        #pragma unroll
        for (int j = 0; j < 8; ++j) {
            xb[0][j] = __bfloat162float(xp[(size_t)j * HS_]);
            xb[1][j] = __bfloat162float(xp[(size_t)(8 + j) * HS_]);
        }
        wAr[0] = wact ? wb[il * HW_ + jl] : 0.0f;
        wAr[1] = wact ? wb[il * HW_ + 8 + jl] : 0.0f;
        float A = xb[0][0];
        #pragma unroll
        for (int cc = 0; cc < 8; ++cc) {
            const int buf = cc % 3;
            if (cc < 6) {                 // prefetch 2 chunks ahead
                const int nb = (cc + 2) % 3;
                #pragma unroll
                for (int j = 0; j < 8; ++j)
                    xb[nb][j] = __bfloat162float(xp[(size_t)((cc + 2) * 8 + j) * HS_]);
                wAr[nb] = wact ? wb[il * HW_ + (cc + 2) * 8 + jl] : 0.0f;
            }
            #pragma unroll
            for (int j = 0; j < 8; ++j) {
                A = sga_step_dpp(A, xb[buf][j], rl(wAr[buf], j), rl(wAr[buf], 8 + j),
                                 rl(wAr[buf], 16 + j), rl(wAr[buf], 24 + j),
                                 rl(wAr[buf], 32 + j), actv, ge47);
                if (actv) sA[colb][0][cc * 8 + j][d] = (__fp16)A;
            }
        }
    } else {
        // ---- reverse scan h = 63..0 ----
        #pragma unroll
        for (int j = 0; j < 8; ++j) {
            xb[0][j] = __bfloat162float(xp[(size_t)(56 + j) * HS_]);
            xb[1][j] = __bfloat162float(xp[(size_t)(48 + j) * HS_]);
        }
        wAr[0] = wact ? wb[il * HW_ + 56 + jl] : 0.0f;
        wAr[1] = wact ? wb[il * HW_ + 48 + jl] : 0.0f;
        float A = xb[0][7];
        #pragma unroll
        for (int cc2 = 0; cc2 < 8; ++cc2) {
            const int cc = 7 - cc2;       // chunk base descending
            const int buf = cc2 % 3;
            if (cc2 < 6) {
                const int nb = (cc2 + 2) % 3;
                #pragma unroll
                for (int j = 0; j < 8; ++j)
                    xb[nb][j] = __bfloat162float(xp[(size_t)((cc - 2) * 8 + j) * HS_]);
                wAr[nb] = wact ? wb[il * HW_ + (cc - 2) * 8 + jl] : 0.0f;
            }
            #pragma unroll
            for (int j = 7; j >= 0; --j) {
                A = sga_step_dpp(A, xb[buf][j], rl(wAr[buf], j), rl(wAr[buf], 8 + j),
                                 rl(wAr[buf], 16 + j), rl(wAr[buf], 24 + j),
                                 rl(wAr[buf], 32 + j), actv, ge47);
                if (actv) sA[colb][1][cc * 8 + j][d] = (__fp16)A;
            }
        }
    }

    __syncthreads();

    // ---- merge: this wave handles its column, h in [dir*32, dir*32+32) ----
    float s1 = g1[c] * rsqrtf(v1[c] + EPS_);
    float o1 = b1[c] - m1[c] * s1;
    __hip_bfloat16* dp = d12 + ((size_t)c * HW_ + w) * 48 + d;
    #pragma unroll
    for (int t = 0; t < 32; ++t) {
        int h = dir * 32 + t;
        float dv = __bfloat162float(dp[(size_t)h * HS_]);
        float d3 = (float)sA[colb][0][h][d];
        float d4 = (float)sA[colb][1][h][d];
        float comb = fmaxf(fmaxf(d3, d4), dv);
        if (actv)
            dp[(size_t)h * HS_] = __float2bfloat16(fmaxf(comb * s1 + o1, 0.0f));
    }
}

// ---------------------------------------------------------------------------
// trans: st bf16 [c][h][w][d] -> act bf16 [h][DP][WP][c], d,w shifted +1
// ---------------------------------------------------------------------------
__global__ __launch_bounds__(256) void trans_kernel(
    const __hip_bfloat16* __restrict__ st, __hip_bfloat16* __restrict__ act)
{
    __shared__ float t[8 * 1571];   // addr = wl*1571 + c*49 + d
    int tid = threadIdx.x;
    int h  = blockIdx.x / 26;
    int w0 = (blockIdx.x % 26) * 8;
    const unsigned* stu = (const unsigned*)st;
    #pragma unroll
    for (int k = 0; k < 24; ++k) {
        int f = tid + 256 * k;              // < 6144
        int d2 = f % 24, wl = (f / 24) % 8, c = f / 192;
        unsigned u = stu[(((size_t)c * HW_ + h * W_ + w0 + wl) * 48 + 2 * d2) >> 1];
        const __hip_bfloat16* bp = (const __hip_bfloat16*)&u;
        t[wl * 1571 + c * 49 + 2 * d2]     = __bfloat162float(bp[0]);
        t[wl * 1571 + c * 49 + 2 * d2 + 1] = __bfloat162float(bp[1]);
    }
    __syncthreads();
    unsigned* actu = (unsigned*)act;
    #pragma unroll
    for (int k = 0; k < 24; ++k) {
        int f = tid + 256 * k;              // < 6144
        int cp = f % 16, wl = (f / 16) % 8, d = f / 128;
        union { unsigned u; __hip_bfloat16 hh[2]; } pk;
        pk.hh[0] = __float2bfloat16(t[wl * 1571 + (2 * cp) * 49 + d]);
        pk.hh[1] = __float2bfloat16(t[wl * 1571 + (2 * cp + 1) * 49 + d]);
        actu[(((size_t)h * DP_ + d + 1) * WP_ + w0 + wl + 1) * 16 + cp] = pk.u;
    }
}

// ---------------------------------------------------------------------------
// Conv 3x3x3, block-cooperative LDS-staged implicit GEMM (MFMA 32x32x16).
// Block = 4 waves = 32co x 32w x 8d. Per kh-row: stage act brick
// [10 dp][34 wl][32 c] (c padded to 40 in LDS for bank spread) once, then
// each wave (2 d-planes, 32 AGPR acc) streams ds_read_b128 + MFMA.
// act is d- AND w-zero-padded -> no boundary logic anywhere.
// ---------------------------------------------------------------------------
__global__ __launch_bounds__(256, 4) void conv_kernel(
    const __hip_bfloat16* __restrict__ act,   // [H][DP][WP][C]
    const short8* __restrict__ wrep,          // [27][2][64] short8
    const float* __restrict__ x,
    const float* __restrict__ g2, const float* __restrict__ b2,
    const float* __restrict__ m2, const float* __restrict__ v2,
    float* __restrict__ out)
{
    __shared__ __hip_bfloat16 sAct[10 * 34 * 40];

    int tid  = threadIdx.x;
    int lane = tid & 63;
    int v    = tid >> 6;                 // wave 0..3
    int bid  = blockIdx.x;
    int wt   = bid % 7;
    int t    = bid / 7;
    int h    = t & 63;
    int d0b  = (t >> 6) * 8;             // block d-base: 0,8,...,40
    int w0   = wt * 32;
    int n    = lane & 31;
    int half = lane >> 5;

    float16v acc0 = (float16v)(0.0f);
    float16v acc1 = (float16v)(0.0f);

    const short8* ap8 = (const short8*)act;

    #pragma unroll
    for (int kh = 0; kh < 3; ++kh) {
        int hh = h + kh - 1;
        if (hh < 0 || hh >= H_) continue;          // block-uniform
        __syncthreads();                           // prev-iter reads done
        #pragma unroll
        for (int k = 0; k < 6; ++k) {
            int i = tid + 256 * k;                 // 1360 chunks of 16B
            if (i < 1360) {
                int dp = i / 136;
                int r  = i - dp * 136;
                int wl = r >> 2, q = r & 3;
                int wc = w0 + wl; wc = wc < 209 ? wc : 209;   // clamp to zero col
                short8 vd = ap8[(((size_t)hh * DP_ + d0b + dp) * WP_ + wc) * 4 + q];
                *(short8*)&sAct[(dp * 34 + wl) * 40 + q * 8] = vd;
            }
        }
        __syncthreads();
        #pragma unroll
        for (int kw = 0; kw < 3; ++kw) {
            #pragma unroll
            for (int cih = 0; cih < 2; ++cih) {
                short8 af[3];
                #pragma unroll
                for (int kd = 0; kd < 3; ++kd)
                    af[kd] = wrep[(((kd*3 + kh)*3 + kw)*2 + cih)*64 + lane];
                short8 bf[4];
                #pragma unroll
                for (int p = 0; p < 4; ++p)
                    bf[p] = *(const short8*)
                        &sAct[((2*v + p) * 34 + kw + n) * 40 + cih * 16 + half * 8];
                #pragma unroll
                for (int kd = 0; kd < 3; ++kd) {
                    acc0 = __builtin_amdgcn_mfma_f32_32x32x16_bf16(af[kd], bf[kd],   acc0, 0, 0, 0);
                    acc1 = __builtin_amdgcn_mfma_f32_32x32x16_bf16(af[kd], bf[kd+1], acc1, 0, 0, 0);
                }
            }
        }
    }

    int d0 = d0b + 2 * v;
    int wl = w0 + n;
    bool wvalid = wl < W_;
    int coh = 4 * half;
    #pragma unroll
    for (int r = 0; r < 16; ++r) {
        int co = (r & 3) + 8 * (r >> 2) + coh;
        float s2 = g2[co] * rsqrtf(v2[co] + EPS_);
        float o2 = b2[co] - m2[co] * s2;
        size_t idx0 = ((size_t)(co * D_ + d0) * H_ + h) * W_ + wl;
        if (wvalid) {
            out[idx0]       = fmaxf(acc0[r] * s2 + o2 + x[idx0],       0.0f);
            out[idx0 + HW_] = fmaxf(acc1[r] * s2 + o2 + x[idx0 + HW_], 0.0f);
        }
    }
}

// ---------------------------------------------------------------------------
extern "C" void kernel_launch(void* const* d_in, const int* in_sizes, int n_in,
                              void* d_out, int out_size, void* d_ws, size_t ws_size,
                              hipStream_t stream)
{
    const float* x    = (const float*)d_in[0];
    const float* g    = (const float*)d_in[1];
    const float* cw   = (const float*)d_in[2];
    const float* bn1g = (const float*)d_in[3];
    const float* bn1b = (const float*)d_in[4];
    const float* bn1m = (const float*)d_in[5];
    const float* bn1v = (const float*)d_in[6];
    const float* bn2g = (const float*)d_in[7];
    const float* bn2b = (const float*)d_in[8];
    const float* bn2m = (const float*)d_in[9];
    const float* bn2v = (const float*)d_in[10];
    float* out = (float*)d_out;

    char* ws = (char*)d_ws;
    float* wn  = (float*)ws;                                   // 1,064,960 B
    float* wnT = (float*)(ws + 1064960);                       //   532,480 B
    __hip_bfloat16* wrep = (__hip_bfloat16*)(ws + 1597440);    //    55,296 B
    __hip_bfloat16* d12t = (__hip_bfloat16*)(ws + 1652736);    // 40,894,464 B
    __hip_bfloat16* act  = (__hip_bfloat16*)(ws + 42547200);   // 43,008,000 B (d+w padded)
    __hip_bfloat16* xt = (__hip_bfloat16*)out;  // d_out as bf16 xt scratch

    prep_kernel<<<2380, 256, 0, stream>>>(g, cw, wn, wnT, wrep, (unsigned*)act);
    t0_kernel<<<1664, 256, 0, stream>>>(x, xt);
    sga_w_kernel<<<1024, 256, 0, stream>>>(xt, wn, d12t);
    sga_h_kernel<<<3328, 256, 0, stream>>>(xt, wnT, d12t, bn1g, bn1b, bn1m, bn1v);
    trans_kernel<<<1664, 256, 0, stream>>>(d12t, act);
    conv_kernel<<<2688, 256, 0, stream>>>(act, (const short8*)wrep, x,
                                          bn2g, bn2b, bn2m, bn2v, out);
}

// Round 11
// 397.385 us; speedup vs baseline: 1.2700x; 1.0366x over previous
//
#include <hip/hip_runtime.h>
#include <hip/hip_bf16.h>
#include <cstddef>

#define C_ 32
#define D_ 48
#define DP_ 50               // padded act depth: plane 0 = d=-1 zeros, plane 49 = d=48 zeros
#define H_ 64
#define W_ 208
#define WP_ 210              // padded act width: col 0 = w=-1 zeros, col 209 = w=208 zeros
#define HW_ 13312            // H_*W_
#define HS_ 9984             // W_*48, xt h-stride
#define EPS_ 1e-5f

typedef __attribute__((ext_vector_type(8))) short short8;
typedef __attribute__((ext_vector_type(4))) float float4v;
typedef __attribute__((ext_vector_type(16))) float float16v;
typedef __attribute__((ext_vector_type(2))) __fp16 half2v;

// ---------------------------------------------------------------------------
// DPP helpers (VALU-latency cross-lane; invalid lanes keep old = src)
// ---------------------------------------------------------------------------
template<int CTRL>
__device__ __forceinline__ float dppmov(float x) {
    int v = __builtin_bit_cast(int, x);
    return __builtin_bit_cast(float,
        __builtin_amdgcn_update_dpp(v, v, CTRL, 0xf, 0xf, false));
}
template<int CTRL>
__device__ __forceinline__ float dppmax(float m) {
    return fmaxf(m, dppmov<CTRL>(m));
}
__device__ __forceinline__ float rl(float v, int idx) {
    return __builtin_bit_cast(float,
        __builtin_amdgcn_readlane(__builtin_bit_cast(int, v), idx));
}
template<int CTRL>
__device__ __forceinline__ unsigned dppu(unsigned x) {
    return (unsigned)__builtin_amdgcn_update_dpp((int)x, (int)x, CTRL, 0xf, 0xf, false);
}
__device__ __forceinline__ unsigned rlu(unsigned v, int idx) {
    return (unsigned)__builtin_amdgcn_readlane((int)v, idx);
}
__device__ __forceinline__ unsigned pkmax_u(unsigned a, unsigned b) {
    unsigned r;
    asm("v_pk_max_f16 %0, %1, %2" : "=v"(r) : "v"(a), "v"(b));
    return r;
}
__device__ __forceinline__ half2v hcast(unsigned u) { return __builtin_bit_cast(half2v, u); }
__device__ __forceinline__ unsigned ucast(half2v h) { return __builtin_bit_cast(unsigned, h); }

// One SGA recurrence step, fp32 scalar (lane = d) — used by sga_w.
__device__ __forceinline__ float sga_step_dpp(float A, float xi,
    float w0, float w1, float w2, float w3, float w4, bool actv, bool ge47)
{
    float up = dppmov<0x138>(A);             // wave_shr:1, lane0 keeps A (d=0 clamp)
    float dn = dppmov<0x130>(A);             // wave_shl:1
    dn = ge47 ? A : dn;                      // d=47 clamp
    float m = actv ? A : -3.4e38f;
    m = dppmax<0x111>(m);
    m = dppmax<0x112>(m);
    m = dppmax<0x114>(m);
    m = dppmax<0x118>(m);
    m = dppmax<0x142>(m);
    m = dppmax<0x143>(m);
    float mall = rl(m, 63);
    return (w0*xi + w1*A) + ((w2*up + w3*dn) + w4*mall);
}

// One SGA recurrence step, packed fp16: both halves = two columns, lane = d.
__device__ __forceinline__ unsigned sga_step_pk(unsigned Au, unsigned xiu,
    unsigned w0, unsigned w1, unsigned w2, unsigned w3, unsigned w4,
    bool actv, bool ge47)
{
    unsigned up = dppu<0x138>(Au);
    unsigned dn = dppu<0x130>(Au);
    dn = ge47 ? Au : dn;
    unsigned m = actv ? Au : 0xFBFFFBFFu;    // -65504 in both halves
    m = pkmax_u(m, dppu<0x111>(m));
    m = pkmax_u(m, dppu<0x112>(m));
    m = pkmax_u(m, dppu<0x114>(m));
    m = pkmax_u(m, dppu<0x118>(m));
    m = pkmax_u(m, dppu<0x142>(m));
    m = pkmax_u(m, dppu<0x143>(m));
    unsigned mall = rlu(m, 63);
    half2v A = hcast(Au), xi = hcast(xiu), uph = hcast(up), dnh = hcast(dn),
           mh = hcast(mall), h0 = hcast(w0), h1 = hcast(w1), h2 = hcast(w2),
           h3 = hcast(w3), h4 = hcast(w4);
    half2v r = (h0 * xi + h1 * A) + ((h2 * uph + h3 * dnh) + h4 * mh);
    return ucast(r);
}

// ---------------------------------------------------------------------------
// Prep: L1-normalize guidance; transpose H-scan weights; repack conv weights;
// zero-fill act's 2 pad cols (per real plane) and 2 pad planes.
// ---------------------------------------------------------------------------
__global__ __launch_bounds__(256) void prep_kernel(
    const float* __restrict__ g, const float* __restrict__ cw,
    float* __restrict__ wn, float* __restrict__ wnT,
    __hip_bfloat16* __restrict__ wrep, unsigned* __restrict__ actu)
{
    int idx = blockIdx.x * 256 + threadIdx.x;
    if (idx < 4 * HW_) {
        int dir = idx / HW_;
        int hw  = idx % HW_;
        const float* gb = g + dir * 5 * HW_ + hw;
        float v0 = gb[0*HW_], v1 = gb[1*HW_], v2 = gb[2*HW_], v3 = gb[3*HW_], v4 = gb[4*HW_];
        float s = fabsf(v0)+fabsf(v1)+fabsf(v2)+fabsf(v3)+fabsf(v4);
        float inv = 1.0f / fmaxf(s, 1e-12f);
        v0 *= inv; v1 *= inv; v2 *= inv; v3 *= inv; v4 *= inv;
        float* ob = wn + dir * 5 * HW_ + hw;
        ob[0*HW_] = v0; ob[1*HW_] = v1; ob[2*HW_] = v2; ob[3*HW_] = v3; ob[4*HW_] = v4;
        if (dir >= 2) {   // H-scan dirs: also write [dd][i][w][h]
            int hq = hw / W_, wq = hw % W_;
            float* oT = wnT + ((size_t)((dir-2)*5)*W_ + wq)*H_ + hq;
            oT[0]       = v0; oT[1*HW_] = v1; oT[2*HW_] = v2;
            oT[3*HW_]   = v3; oT[4*HW_] = v4;   // i-stride = W_*H_ = HW_
        }
    } else if (idx < 4 * HW_ + 27648) {
        int j = idx - 4 * HW_;
        int e    = j & 7;
        int lane = (j >> 3) & 63;
        int q    = j >> 9;            // 0..53
        int cih  = q & 1;
        int tap  = q >> 1;
        int co = lane & 31;
        int ci = cih * 16 + (lane >> 5) * 8 + e;
        wrep[j] = __float2bfloat16(cw[(co * C_ + ci) * 27 + tap]);
    } else if (idx < 4 * HW_ + 27648 + 98304) {
        int j2 = idx - (4 * HW_ + 27648);   // w-pad cols of the 48 real planes
        int hd  = j2 >> 5;                  // h*48 + dd, in [0,3072)
        int r   = j2 & 31;
        int col = (r >> 4) ? 209 : 0;
        int cu  = r & 15;
        int h = hd / 48, dd = hd % 48;
        actu[(((size_t)h * DP_ + dd + 1) * WP_ + col) * 16 + cu] = 0u;
    } else {
        int j3 = idx - (4 * HW_ + 27648 + 98304);   // [0, 430080): 2 d-pad planes
        int pl   = j3 >= 215040;            // 215040 = 64*210*16
        int r3   = pl ? j3 - 215040 : j3;
        int h    = r3 / 3360;               // 3360 = 210*16
        int rest = r3 % 3360;
        int dpad = pl ? (DP_ - 1) : 0;
        actu[((size_t)h * DP_ + dpad) * WP_ * 16 + rest] = 0u;
    }
}

// ---------------------------------------------------------------------------
// t0: transpose x [c][d][h][w] fp32 -> xt [c][h][w][d] bf16 (lives in d_out)
// ---------------------------------------------------------------------------
__global__ __launch_bounds__(256) void t0_kernel(
    const float* __restrict__ x, __hip_bfloat16* __restrict__ xt)
{
    __shared__ float t[48 * 257];
    int tid = threadIdx.x;
    int c  = blockIdx.x / 52;
    int q0 = (blockIdx.x % 52) * 256;
    #pragma unroll
    for (int dd = 0; dd < 48; ++dd)
        t[dd * 257 + tid] = x[((size_t)c * 48 + dd) * HW_ + q0 + tid];
    __syncthreads();
    unsigned* xtu = (unsigned*)xt;
    #pragma unroll
    for (int k = 0; k < 24; ++k) {
        int f = tid + 256 * k;              // < 6144 bf16-pairs
        int d2 = f % 24, hwl = f / 24;
        union { unsigned u; __hip_bfloat16 hh[2]; } pk;
        pk.hh[0] = __float2bfloat16(t[(2 * d2) * 257 + hwl]);
        pk.hh[1] = __float2bfloat16(t[(2 * d2 + 1) * 257 + hwl]);
        xtu[(((size_t)c * HW_ + q0 + hwl) * 48 + 2 * d2) >> 1] = pk.u;
    }
}

// ---------------------------------------------------------------------------
// Horizontal scans, fwd/rev SPLIT, all-LDS (proven round-10 version).
// ---------------------------------------------------------------------------
__global__ __launch_bounds__(256, 4) void sga_w_kernel(
    const __hip_bfloat16* __restrict__ xt, const float* __restrict__ wn,
    __hip_bfloat16* __restrict__ d12)
{
    __shared__ __fp16 sO[2][2][208][48];   // [rowb][dir][p][d]

    int lane = threadIdx.x & 63;
    int widb = threadIdx.x >> 6;          // 0..3
    int rowb = widb >> 1;                 // row within block
    int dir  = widb & 1;                  // 0 = fwd (d1), 1 = rev (d2)
    int grow = blockIdx.x * 2 + rowb;     // 0..2047
    int c = grow >> 6, h = grow & 63;
    int d = lane < 48 ? lane : 47;
    bool actv = lane < 48, ge47 = lane >= 47;
    const __hip_bfloat16* xp = xt + ((size_t)c * HW_ + h * W_) * 48 + d;   // + p*48
    const float* wb = wn + (size_t)dir * 5 * HW_ + h * W_;                 // + i*HW_ + p
    int il = lane >> 3, jl = lane & 7;    // weight gather: lane il*8+jl -> dir il, offset jl
    bool wact = il < 5;

    float xb[3][8];
    float wAr[3];

    if (dir == 0) {
        // ---- forward scan p = 0..207 ----
        #pragma unroll
        for (int j = 0; j < 8; ++j) {
            xb[0][j] = __bfloat162float(xp[(size_t)j * 48]);
            xb[1][j] = __bfloat162float(xp[(size_t)(8 + j) * 48]);
        }
        wAr[0] = wact ? wb[il * HW_ + jl] : 0.0f;
        wAr[1] = wact ? wb[il * HW_ + 8 + jl] : 0.0f;
        float A = xb[0][0];
        #pragma unroll
        for (int cc = 0; cc < 26; ++cc) {
            const int buf = cc % 3;
            if (cc < 24) {                // prefetch 2 chunks ahead
                const int nb = (cc + 2) % 3;
                #pragma unroll
                for (int j = 0; j < 8; ++j)
                    xb[nb][j] = __bfloat162float(xp[(size_t)((cc + 2) * 8 + j) * 48]);
                wAr[nb] = wact ? wb[il * HW_ + (cc + 2) * 8 + jl] : 0.0f;
            }
            #pragma unroll
            for (int j = 0; j < 8; ++j) {
                A = sga_step_dpp(A, xb[buf][j], rl(wAr[buf], j), rl(wAr[buf], 8 + j),
                                 rl(wAr[buf], 16 + j), rl(wAr[buf], 24 + j),
                                 rl(wAr[buf], 32 + j), actv, ge47);
                if (actv) sO[rowb][0][cc * 8 + j][d] = (__fp16)A;
            }
        }
    } else {
        // ---- reverse scan p = 207..0 ----
        #pragma unroll
        for (int j = 0; j < 8; ++j) {
            xb[0][j] = __bfloat162float(xp[(size_t)(200 + j) * 48]);
            xb[1][j] = __bfloat162float(xp[(size_t)(192 + j) * 48]);
        }
        wAr[0] = wact ? wb[il * HW_ + 200 + jl] : 0.0f;
        wAr[1] = wact ? wb[il * HW_ + 192 + jl] : 0.0f;
        float A = xb[0][7];
        #pragma unroll
        for (int cc2 = 0; cc2 < 26; ++cc2) {
            const int cc = 25 - cc2;
            const int buf = cc2 % 3;
            if (cc2 < 24) {               // prefetch 2 chunks ahead (descending)
                const int nb = (cc2 + 2) % 3;
                #pragma unroll
                for (int j = 0; j < 8; ++j)
                    xb[nb][j] = __bfloat162float(xp[(size_t)((cc - 2) * 8 + j) * 48]);
                wAr[nb] = wact ? wb[il * HW_ + (cc - 2) * 8 + jl] : 0.0f;
            }
            #pragma unroll
            for (int j = 7; j >= 0; --j) {
                A = sga_step_dpp(A, xb[buf][j], rl(wAr[buf], j), rl(wAr[buf], 8 + j),
                                 rl(wAr[buf], 16 + j), rl(wAr[buf], 24 + j),
                                 rl(wAr[buf], 32 + j), actv, ge47);
                if (actv) sO[rowb][1][cc * 8 + j][d] = (__fp16)A;
            }
        }
    }

    __syncthreads();

    // ---- merge: wave (rowb,dir) handles p in [dir*104, dir*104+104) ----
    __hip_bfloat16* dp = d12 + ((size_t)c * HW_ + h * W_) * 48 + d;
    if (actv) {
        const int p0 = dir * 104;
        #pragma unroll
        for (int t = 0; t < 104; ++t) {
            int p = p0 + t;
            float d1 = (float)sO[rowb][0][p][d];
            float d2 = (float)sO[rowb][1][p][d];
            dp[(size_t)p * 48] = __float2bfloat16(fmaxf(d1, d2));
        }
    }
}

// ---------------------------------------------------------------------------
// Vertical scans, PACKED fp16: each wave handles TWO adjacent columns
// (g0=2*gp, g1=2*gp+1 — always same c since W is even) with both columns
// packed in the halves of one 32-bit reg. v_pk_max_f16 reduce, v_pk_fma_f16
// recurrence: ~half the VALU instructions per column vs fp32 scalar.
// Block = 128 threads = 2 waves {fwd, rev}; results meet in LDS (packed);
// merge applies max(d3,d4,d12) + BN1 + ReLU for both columns.
// ---------------------------------------------------------------------------
__global__ __launch_bounds__(128, 3) void sga_h_kernel(
    const __hip_bfloat16* __restrict__ xt, const float* __restrict__ wnT,
    __hip_bfloat16* __restrict__ d12,
    const float* __restrict__ g1, const float* __restrict__ b1,
    const float* __restrict__ m1, const float* __restrict__ v1)
{
    __shared__ unsigned sO[2][64][48];    // [dir][h][d] packed {colA,colB}

    int lane = threadIdx.x & 63;
    int dir  = threadIdx.x >> 6;          // 0 = fwd (d3), 1 = rev (d4)
    int gp   = blockIdx.x;                // 0..3327 column pair
    int g0 = gp * 2;
    int c = g0 / W_, w = g0 % W_;         // colB = w+1, same c (W even)
    int d = lane < 48 ? lane : 47;
    bool actv = lane < 48, ge47 = lane >= 47;
    const __hip_bfloat16* xA = xt + ((size_t)c * HW_ + w) * 48 + d;   // + h*HS_
    const __hip_bfloat16* xB = xA + 48;
    const float* wbA = wnT + ((size_t)(dir * 5) * W_ + w) * H_;       // + i*HW_ + h
    const float* wbB = wbA + H_;
    int il = lane >> 3, jl = lane & 7;    // weight gather lane layout
    bool wact = il < 5;

    unsigned xpk[3][8];
    unsigned wAr[3];

    if (dir == 0) {
        // ---- forward scan h = 0..63 ----
        #pragma unroll
        for (int b = 0; b < 2; ++b) {
            #pragma unroll
            for (int j = 0; j < 8; ++j) {
                float fA = __bfloat162float(xA[(size_t)(b * 8 + j) * HS_]);
                float fB = __bfloat162float(xB[(size_t)(b * 8 + j) * HS_]);
                xpk[b][j] = ucast(__builtin_amdgcn_cvt_pkrtz(fA, fB));
            }
            float wfA = wact ? wbA[il * HW_ + b * 8 + jl] : 0.0f;
            float wfB = wact ? wbB[il * HW_ + b * 8 + jl] : 0.0f;
            wAr[b] = ucast(__builtin_amdgcn_cvt_pkrtz(wfA, wfB));
        }
        unsigned Au = xpk[0][0];
        #pragma unroll
        for (int cc = 0; cc < 8; ++cc) {
            const int buf = cc % 3;
            if (cc < 6) {                 // prefetch 2 chunks ahead
                const int nb = (cc + 2) % 3;
                #pragma unroll
                for (int j = 0; j < 8; ++j) {
                    float fA = __bfloat162float(xA[(size_t)((cc + 2) * 8 + j) * HS_]);
                    float fB = __bfloat162float(xB[(size_t)((cc + 2) * 8 + j) * HS_]);
                    xpk[nb][j] = ucast(__builtin_amdgcn_cvt_pkrtz(fA, fB));
                }
                float wfA = wact ? wbA[il * HW_ + (cc + 2) * 8 + jl] : 0.0f;
                float wfB = wact ? wbB[il * HW_ + (cc + 2) * 8 + jl] : 0.0f;
                wAr[nb] = ucast(__builtin_amdgcn_cvt_pkrtz(wfA, wfB));
            }
            #pragma unroll
            for (int j = 0; j < 8; ++j) {
                Au = sga_step_pk(Au, xpk[buf][j], rlu(wAr[buf], j), rlu(wAr[buf], 8 + j),
                                 rlu(wAr[buf], 16 + j), rlu(wAr[buf], 24 + j),
                                 rlu(wAr[buf], 32 + j), actv, ge47);
                if (actv) sO[0][cc * 8 + j][d] = Au;
            }
        }
    } else {
        // ---- reverse scan h = 63..0 ----
        #pragma unroll
        for (int b = 0; b < 2; ++b) {
            const int base = 56 - b * 8;
            #pragma unroll
            for (int j = 0; j < 8; ++j) {
                float fA = __bfloat162float(xA[(size_t)(base + j) * HS_]);
                float fB = __bfloat162float(xB[(size_t)(base + j) * HS_]);
                xpk[b][j] = ucast(__builtin_amdgcn_cvt_pkrtz(fA, fB));
            }
            float wfA = wact ? wbA[il * HW_ + base + jl] : 0.0f;
            float wfB = wact ? wbB[il * HW_ + base + jl] : 0.0f;
            wAr[b] = ucast(__builtin_amdgcn_cvt_pkrtz(wfA, wfB));
        }
        unsigned Au = xpk[0][7];
        #pragma unroll
        for (int cc2 = 0; cc2 < 8; ++cc2) {
            const int cc = 7 - cc2;       // chunk base descending
            const int buf = cc2 % 3;
            if (cc2 < 6) {
                const int nb = (cc2 + 2) % 3;
                #pragma unroll
                for (int j = 0; j < 8; ++j) {
                    float fA = __bfloat162float(xA[(size_t)((cc - 2) * 8 + j) * HS_]);
                    float fB = __bfloat162float(xB[(size_t)((cc - 2) * 8 + j) * HS_]);
                    xpk[nb][j] = ucast(__builtin_amdgcn_cvt_pkrtz(fA, fB));
                }
                float wfA = wact ? wbA[il * HW_ + (cc - 2) * 8 + jl] : 0.0f;
                float wfB = wact ? wbB[il * HW_ + (cc - 2) * 8 + jl] : 0.0f;
                wAr[nb] = ucast(__builtin_amdgcn_cvt_pkrtz(wfA, wfB));
            }
            #pragma unroll
            for (int j = 7; j >= 0; --j) {
                Au = sga_step_pk(Au, xpk[buf][j], rlu(wAr[buf], j), rlu(wAr[buf], 8 + j),
                                 rlu(wAr[buf], 16 + j), rlu(wAr[buf], 24 + j),
                                 rlu(wAr[buf], 32 + j), actv, ge47);
                if (actv) sO[1][cc * 8 + j][d] = Au;
            }
        }
    }

    __syncthreads();

    // ---- merge: this wave handles h in [dir*32, dir*32+32), both columns ----
    float s1 = g1[c] * rsqrtf(v1[c] + EPS_);
    float o1 = b1[c] - m1[c] * s1;
    __hip_bfloat16* dpA = d12 + ((size_t)c * HW_ + w) * 48 + d;
    __hip_bfloat16* dpB = dpA + 48;
    #pragma unroll
    for (int t = 0; t < 32; ++t) {
        int h = dir * 32 + t;
        unsigned um = pkmax_u(sO[0][h][d], sO[1][h][d]);
        half2v mh = hcast(um);
        if (actv) {
            float vA = fmaxf((float)mh[0], __bfloat162float(dpA[(size_t)h * HS_]));
            float vB = fmaxf((float)mh[1], __bfloat162float(dpB[(size_t)h * HS_]));
            dpA[(size_t)h * HS_] = __float2bfloat16(fmaxf(vA * s1 + o1, 0.0f));
            dpB[(size_t)h * HS_] = __float2bfloat16(fmaxf(vB * s1 + o1, 0.0f));
        }
    }
}

// ---------------------------------------------------------------------------
// trans: st bf16 [c][h][w][d] -> act bf16 [h][DP][WP][c], d,w shifted +1
// ---------------------------------------------------------------------------
__global__ __launch_bounds__(256) void trans_kernel(
    const __hip_bfloat16* __restrict__ st, __hip_bfloat16* __restrict__ act)
{
    __shared__ float t[8 * 1571];   // addr = wl*1571 + c*49 + d
    int tid = threadIdx.x;
    int h  = blockIdx.x / 26;
    int w0 = (blockIdx.x % 26) * 8;
    const unsigned* stu = (const unsigned*)st;
    #pragma unroll
    for (int k = 0; k < 24; ++k) {
        int f = tid + 256 * k;              // < 6144
        int d2 = f % 24, wl = (f / 24) % 8, c = f / 192;
        unsigned u = stu[(((size_t)c * HW_ + h * W_ + w0 + wl) * 48 + 2 * d2) >> 1];
        const __hip_bfloat16* bp = (const __hip_bfloat16*)&u;
        t[wl * 1571 + c * 49 + 2 * d2]     = __bfloat162float(bp[0]);
        t[wl * 1571 + c * 49 + 2 * d2 + 1] = __bfloat162float(bp[1]);
    }
    __syncthreads();
    unsigned* actu = (unsigned*)act;
    #pragma unroll
    for (int k = 0; k < 24; ++k) {
        int f = tid + 256 * k;              // < 6144
        int cp = f % 16, wl = (f / 16) % 8, d = f / 128;
        union { unsigned u; __hip_bfloat16 hh[2]; } pk;
        pk.hh[0] = __float2bfloat16(t[wl * 1571 + (2 * cp) * 49 + d]);
        pk.hh[1] = __float2bfloat16(t[wl * 1571 + (2 * cp + 1) * 49 + d]);
        actu[(((size_t)h * DP_ + d + 1) * WP_ + w0 + wl + 1) * 16 + cp] = pk.u;
    }
}

// ---------------------------------------------------------------------------
// Conv 3x3x3, block-cooperative LDS-staged implicit GEMM (MFMA 32x32x16).
// Block = 4 waves = 32co x 32w x 8d. Per kh-row: stage act brick
// [10 dp][34 wl][32 c] (c padded to 40 in LDS for bank spread) once, then
// each wave (2 d-planes, 32 AGPR acc) streams ds_read_b128 + MFMA.
// act is d- AND w-zero-padded -> no boundary logic anywhere.
// ---------------------------------------------------------------------------
__global__ __launch_bounds__(256, 4) void conv_kernel(
    const __hip_bfloat16* __restrict__ act,   // [H][DP][WP][C]
    const short8* __restrict__ wrep,          // [27][2][64] short8
    const float* __restrict__ x,
    const float* __restrict__ g2, const float* __restrict__ b2,
    const float* __restrict__ m2, const float* __restrict__ v2,
    float* __restrict__ out)
{
    __shared__ __hip_bfloat16 sAct[10 * 34 * 40];

    int tid  = threadIdx.x;
    int lane = tid & 63;
    int v    = tid >> 6;                 // wave 0..3
    int bid  = blockIdx.x;
    int wt   = bid % 7;
    int t    = bid / 7;
    int h    = t & 63;
    int d0b  = (t >> 6) * 8;             // block d-base: 0,8,...,40
    int w0   = wt * 32;
    int n    = lane & 31;
    int half = lane >> 5;

    float16v acc0 = (float16v)(0.0f);
    float16v acc1 = (float16v)(0.0f);

    const short8* ap8 = (const short8*)act;

    #pragma unroll
    for (int kh = 0; kh < 3; ++kh) {
        int hh = h + kh - 1;
        if (hh < 0 || hh >= H_) continue;          // block-uniform
        __syncthreads();                           // prev-iter reads done
        #pragma unroll
        for (int k = 0; k < 6; ++k) {
            int i = tid + 256 * k;                 // 1360 chunks of 16B
            if (i < 1360) {
                int dp = i / 136;
                int r  = i - dp * 136;
                int wl = r >> 2, q = r & 3;
                int wc = w0 + wl; wc = wc < 209 ? wc : 209;   // clamp to zero col
                short8 vd = ap8[(((size_t)hh * DP_ + d0b + dp) * WP_ + wc) * 4 + q];
                *(short8*)&sAct[(dp * 34 + wl) * 40 + q * 8] = vd;
            }
        }
        __syncthreads();
        #pragma unroll
        for (int kw = 0; kw < 3; ++kw) {
            #pragma unroll
            for (int cih = 0; cih < 2; ++cih) {
                short8 af[3];
                #pragma unroll
                for (int kd = 0; kd < 3; ++kd)
                    af[kd] = wrep[(((kd*3 + kh)*3 + kw)*2 + cih)*64 + lane];
                short8 bf[4];
                #pragma unroll
                for (int p = 0; p < 4; ++p)
                    bf[p] = *(const short8*)
                        &sAct[((2*v + p) * 34 + kw + n) * 40 + cih * 16 + half * 8];
                #pragma unroll
                for (int kd = 0; kd < 3; ++kd) {
                    acc0 = __builtin_amdgcn_mfma_f32_32x32x16_bf16(af[kd], bf[kd],   acc0, 0, 0, 0);
                    acc1 = __builtin_amdgcn_mfma_f32_32x32x16_bf16(af[kd], bf[kd+1], acc1, 0, 0, 0);
                }
            }
        }
    }

    int d0 = d0b + 2 * v;
    int wl = w0 + n;
    bool wvalid = wl < W_;
    int coh = 4 * half;
    #pragma unroll
    for (int r = 0; r < 16; ++r) {
        int co = (r & 3) + 8 * (r >> 2) + coh;
        float s2 = g2[co] * rsqrtf(v2[co] + EPS_);
        float o2 = b2[co] - m2[co] * s2;
        size_t idx0 = ((size_t)(co * D_ + d0) * H_ + h) * W_ + wl;
        if (wvalid) {
            out[idx0]       = fmaxf(acc0[r] * s2 + o2 + x[idx0],       0.0f);
            out[idx0 + HW_] = fmaxf(acc1[r] * s2 + o2 + x[idx0 + HW_], 0.0f);
        }
    }
}

// ---------------------------------------------------------------------------
extern "C" void kernel_launch(void* const* d_in, const int* in_sizes, int n_in,
                              void* d_out, int out_size, void* d_ws, size_t ws_size,
                              hipStream_t stream)
{
    const float* x    = (const float*)d_in[0];
    const float* g    = (const float*)d_in[1];
    const float* cw   = (const float*)d_in[2];
    const float* bn1g = (const float*)d_in[3];
    const float* bn1b = (const float*)d_in[4];
    const float* bn1m = (const float*)d_in[5];
    const float* bn1v = (const float*)d_in[6];
    const float* bn2g = (const float*)d_in[7];
    const float* bn2b = (const float*)d_in[8];
    const float* bn2m = (const float*)d_in[9];
    const float* bn2v = (const float*)d_in[10];
    float* out = (float*)d_out;

    char* ws = (char*)d_ws;
    float* wn  = (float*)ws;                                   // 1,064,960 B
    float* wnT = (float*)(ws + 1064960);                       //   532,480 B
    __hip_bfloat16* wrep = (__hip_bfloat16*)(ws + 1597440);    //    55,296 B
    __hip_bfloat16* d12t = (__hip_bfloat16*)(ws + 1652736);    // 40,894,464 B
    __hip_bfloat16* act  = (__hip_bfloat16*)(ws + 42547200);   // 43,008,000 B (d+w padded)
    __hip_bfloat16* xt = (__hip_bfloat16*)out;  // d_out as bf16 xt scratch

    prep_kernel<<<2380, 256, 0, stream>>>(g, cw, wn, wnT, wrep, (unsigned*)act);
    t0_kernel<<<1664, 256, 0, stream>>>(x, xt);
    sga_w_kernel<<<1024, 256, 0, stream>>>(xt, wn, d12t);
    sga_h_kernel<<<3328, 128, 0, stream>>>(xt, wnT, d12t, bn1g, bn1b, bn1m, bn1v);
    trans_kernel<<<1664, 256, 0, stream>>>(d12t, act);
    conv_kernel<<<2688, 256, 0, stream>>>(act, (const short8*)wrep, x,
                                          bn2g, bn2b, bn2m, bn2v, out);
}

// Round 12
// 382.850 us; speedup vs baseline: 1.3182x; 1.0380x over previous
//
#include <hip/hip_runtime.h>
#include <hip/hip_bf16.h>
#include <cstddef>

#define C_ 32
#define D_ 48
#define DP_ 50               // padded act depth: plane 0 = d=-1 zeros, plane 49 = d=48 zeros
#define H_ 64
#define W_ 208
#define WP_ 210              // padded act width: col 0 = w=-1 zeros, col 209 = w=208 zeros
#define HW_ 13312            // H_*W_
#define HS_ 9984             // W_*48, xt h-stride
#define EPS_ 1e-5f

typedef __attribute__((ext_vector_type(8))) short short8;
typedef __attribute__((ext_vector_type(4))) float float4v;
typedef __attribute__((ext_vector_type(16))) float float16v;
typedef __attribute__((ext_vector_type(2))) __fp16 half2v;

// ---------------------------------------------------------------------------
// DPP helpers (VALU-latency cross-lane; invalid lanes keep old = src)
// ---------------------------------------------------------------------------
template<int CTRL>
__device__ __forceinline__ float dppmov(float x) {
    int v = __builtin_bit_cast(int, x);
    return __builtin_bit_cast(float,
        __builtin_amdgcn_update_dpp(v, v, CTRL, 0xf, 0xf, false));
}
template<int CTRL>
__device__ __forceinline__ float dppmax(float m) {
    return fmaxf(m, dppmov<CTRL>(m));
}
__device__ __forceinline__ float rl(float v, int idx) {
    return __builtin_bit_cast(float,
        __builtin_amdgcn_readlane(__builtin_bit_cast(int, v), idx));
}
template<int CTRL>
__device__ __forceinline__ unsigned dppu(unsigned x) {
    return (unsigned)__builtin_amdgcn_update_dpp((int)x, (int)x, CTRL, 0xf, 0xf, false);
}
__device__ __forceinline__ unsigned rlu(unsigned v, int idx) {
    return (unsigned)__builtin_amdgcn_readlane((int)v, idx);
}
__device__ __forceinline__ unsigned pkmax_u(unsigned a, unsigned b) {
    unsigned r;
    asm("v_pk_max_f16 %0, %1, %2" : "=v"(r) : "v"(a), "v"(b));
    return r;
}
__device__ __forceinline__ half2v hcast(unsigned u) { return __builtin_bit_cast(half2v, u); }
__device__ __forceinline__ unsigned ucast(half2v h) { return __builtin_bit_cast(unsigned, h); }

// One SGA recurrence step, packed fp16: both halves = two scan lines, lane = d.
__device__ __forceinline__ unsigned sga_step_pk(unsigned Au, unsigned xiu,
    unsigned w0, unsigned w1, unsigned w2, unsigned w3, unsigned w4,
    bool actv, bool ge47)
{
    unsigned up = dppu<0x138>(Au);
    unsigned dn = dppu<0x130>(Au);
    dn = ge47 ? Au : dn;
    unsigned m = actv ? Au : 0xFBFFFBFFu;    // -65504 in both halves
    m = pkmax_u(m, dppu<0x111>(m));
    m = pkmax_u(m, dppu<0x112>(m));
    m = pkmax_u(m, dppu<0x114>(m));
    m = pkmax_u(m, dppu<0x118>(m));
    m = pkmax_u(m, dppu<0x142>(m));
    m = pkmax_u(m, dppu<0x143>(m));
    unsigned mall = rlu(m, 63);
    half2v A = hcast(Au), xi = hcast(xiu), uph = hcast(up), dnh = hcast(dn),
           mh = hcast(mall), h0 = hcast(w0), h1 = hcast(w1), h2 = hcast(w2),
           h3 = hcast(w3), h4 = hcast(w4);
    half2v r = (h0 * xi + h1 * A) + ((h2 * uph + h3 * dnh) + h4 * mh);
    return ucast(r);
}

// ---------------------------------------------------------------------------
// Prep: L1-normalize guidance; transpose H-scan weights; repack conv weights;
// zero-fill act's 2 pad cols (per real plane) and 2 pad planes.
// ---------------------------------------------------------------------------
__global__ __launch_bounds__(256) void prep_kernel(
    const float* __restrict__ g, const float* __restrict__ cw,
    float* __restrict__ wn, float* __restrict__ wnT,
    __hip_bfloat16* __restrict__ wrep, unsigned* __restrict__ actu)
{
    int idx = blockIdx.x * 256 + threadIdx.x;
    if (idx < 4 * HW_) {
        int dir = idx / HW_;
        int hw  = idx % HW_;
        const float* gb = g + dir * 5 * HW_ + hw;
        float v0 = gb[0*HW_], v1 = gb[1*HW_], v2 = gb[2*HW_], v3 = gb[3*HW_], v4 = gb[4*HW_];
        float s = fabsf(v0)+fabsf(v1)+fabsf(v2)+fabsf(v3)+fabsf(v4);
        float inv = 1.0f / fmaxf(s, 1e-12f);
        v0 *= inv; v1 *= inv; v2 *= inv; v3 *= inv; v4 *= inv;
        float* ob = wn + dir * 5 * HW_ + hw;
        ob[0*HW_] = v0; ob[1*HW_] = v1; ob[2*HW_] = v2; ob[3*HW_] = v3; ob[4*HW_] = v4;
        if (dir >= 2) {   // H-scan dirs: also write [dd][i][w][h]
            int hq = hw / W_, wq = hw % W_;
            float* oT = wnT + ((size_t)((dir-2)*5)*W_ + wq)*H_ + hq;
            oT[0]       = v0; oT[1*HW_] = v1; oT[2*HW_] = v2;
            oT[3*HW_]   = v3; oT[4*HW_] = v4;   // i-stride = W_*H_ = HW_
        }
    } else if (idx < 4 * HW_ + 27648) {
        int j = idx - 4 * HW_;
        int e    = j & 7;
        int lane = (j >> 3) & 63;
        int q    = j >> 9;            // 0..53
        int cih  = q & 1;
        int tap  = q >> 1;
        int co = lane & 31;
        int ci = cih * 16 + (lane >> 5) * 8 + e;
        wrep[j] = __float2bfloat16(cw[(co * C_ + ci) * 27 + tap]);
    } else if (idx < 4 * HW_ + 27648 + 98304) {
        int j2 = idx - (4 * HW_ + 27648);   // w-pad cols of the 48 real planes
        int hd  = j2 >> 5;                  // h*48 + dd, in [0,3072)
        int r   = j2 & 31;
        int col = (r >> 4) ? 209 : 0;
        int cu  = r & 15;
        int h = hd / 48, dd = hd % 48;
        actu[(((size_t)h * DP_ + dd + 1) * WP_ + col) * 16 + cu] = 0u;
    } else {
        int j3 = idx - (4 * HW_ + 27648 + 98304);   // [0, 430080): 2 d-pad planes
        int pl   = j3 >= 215040;            // 215040 = 64*210*16
        int r3   = pl ? j3 - 215040 : j3;
        int h    = r3 / 3360;               // 3360 = 210*16
        int rest = r3 % 3360;
        int dpad = pl ? (DP_ - 1) : 0;
        actu[((size_t)h * DP_ + dpad) * WP_ * 16 + rest] = 0u;
    }
}

// ---------------------------------------------------------------------------
// t0: transpose x [c][d][h][w] fp32 -> xt [c][h][w][d] bf16 (lives in d_out)
// ---------------------------------------------------------------------------
__global__ __launch_bounds__(256) void t0_kernel(
    const float* __restrict__ x, __hip_bfloat16* __restrict__ xt)
{
    __shared__ float t[48 * 257];
    int tid = threadIdx.x;
    int c  = blockIdx.x / 52;
    int q0 = (blockIdx.x % 52) * 256;
    #pragma unroll
    for (int dd = 0; dd < 48; ++dd)
        t[dd * 257 + tid] = x[((size_t)c * 48 + dd) * HW_ + q0 + tid];
    __syncthreads();
    unsigned* xtu = (unsigned*)xt;
    #pragma unroll
    for (int k = 0; k < 24; ++k) {
        int f = tid + 256 * k;              // < 6144 bf16-pairs
        int d2 = f % 24, hwl = f / 24;
        union { unsigned u; __hip_bfloat16 hh[2]; } pk;
        pk.hh[0] = __float2bfloat16(t[(2 * d2) * 257 + hwl]);
        pk.hh[1] = __float2bfloat16(t[(2 * d2 + 1) * 257 + hwl]);
        xtu[(((size_t)c * HW_ + q0 + hwl) * 48 + 2 * d2) >> 1] = pk.u;
    }
}

// ---------------------------------------------------------------------------
// Horizontal scans, PACKED fp16 row-pairs + fwd/rev split.
// Block = 128 threads = 2 waves {fwd,rev} for one row-pair (h0, h0+1 — same
// c, x/w pointers differ by HS_/W_). Both rows live in the fp16 halves of
// one u32: ~half the VALU instructions per row. fwd streams packed d1 to a
// global staging buffer (d1tmp, L2-resident: same CU re-reads after one
// barrier); rev stores packed d2 to LDS (39,936 B -> 4 blocks/CU = 8
// waves/CU). Merge: pkmax(d1,d2) -> 2 bf16 stores, d12 written once.
// ---------------------------------------------------------------------------
__global__ __launch_bounds__(128, 2) void sga_w_kernel(
    const __hip_bfloat16* __restrict__ xt, const float* __restrict__ wn,
    __hip_bfloat16* __restrict__ d12, unsigned* __restrict__ d1tmp)
{
    __shared__ unsigned sO[208][48];      // rev results, packed {rowA,rowB}

    int lane = threadIdx.x & 63;
    int dir  = threadIdx.x >> 6;          // 0 = fwd (d1), 1 = rev (d2)
    int pairI = blockIdx.x;               // 0..1023
    int c  = pairI >> 5;
    int h0 = (pairI & 31) * 2;
    int d = lane < 48 ? lane : 47;
    bool actv = lane < 48, ge47 = lane >= 47;
    const __hip_bfloat16* xA = xt + ((size_t)c * HW_ + h0 * W_) * 48 + d;  // + p*48
    const __hip_bfloat16* xB = xA + HS_;                                   // row h0+1
    const float* wbA = wn + (size_t)dir * 5 * HW_ + h0 * W_;               // + i*HW_ + p
    int il = lane >> 3, jl = lane & 7;    // weight gather lane layout
    bool wact = il < 5;
    unsigned* tmpp = d1tmp + (size_t)pairI * 208 * 48 + d;

    unsigned xpk[3][8];
    unsigned wAr[3];

    if (dir == 0) {
        // ---- forward scan p = 0..207; stream packed d1 to d1tmp ----
        #pragma unroll
        for (int b = 0; b < 2; ++b) {
            #pragma unroll
            for (int j = 0; j < 8; ++j) {
                float fA = __bfloat162float(xA[(size_t)(b * 8 + j) * 48]);
                float fB = __bfloat162float(xB[(size_t)(b * 8 + j) * 48]);
                xpk[b][j] = ucast(__builtin_amdgcn_cvt_pkrtz(fA, fB));
            }
            float wfA = wact ? wbA[il * HW_ + b * 8 + jl] : 0.0f;
            float wfB = wact ? wbA[il * HW_ + W_ + b * 8 + jl] : 0.0f;
            wAr[b] = ucast(__builtin_amdgcn_cvt_pkrtz(wfA, wfB));
        }
        unsigned Au = xpk[0][0];
        #pragma unroll
        for (int cc = 0; cc < 26; ++cc) {
            const int buf = cc % 3;
            if (cc < 24) {                // prefetch 2 chunks ahead
                const int nb = (cc + 2) % 3;
                #pragma unroll
                for (int j = 0; j < 8; ++j) {
                    float fA = __bfloat162float(xA[(size_t)((cc + 2) * 8 + j) * 48]);
                    float fB = __bfloat162float(xB[(size_t)((cc + 2) * 8 + j) * 48]);
                    xpk[nb][j] = ucast(__builtin_amdgcn_cvt_pkrtz(fA, fB));
                }
                float wfA = wact ? wbA[il * HW_ + (cc + 2) * 8 + jl] : 0.0f;
                float wfB = wact ? wbA[il * HW_ + W_ + (cc + 2) * 8 + jl] : 0.0f;
                wAr[nb] = ucast(__builtin_amdgcn_cvt_pkrtz(wfA, wfB));
            }
            #pragma unroll
            for (int j = 0; j < 8; ++j) {
                Au = sga_step_pk(Au, xpk[buf][j], rlu(wAr[buf], j), rlu(wAr[buf], 8 + j),
                                 rlu(wAr[buf], 16 + j), rlu(wAr[buf], 24 + j),
                                 rlu(wAr[buf], 32 + j), actv, ge47);
                if (actv) tmpp[(size_t)(cc * 8 + j) * 48] = Au;
            }
        }
    } else {
        // ---- reverse scan p = 207..0; packed d2 -> LDS ----
        #pragma unroll
        for (int b = 0; b < 2; ++b) {
            const int base = 200 - b * 8;
            #pragma unroll
            for (int j = 0; j < 8; ++j) {
                float fA = __bfloat162float(xA[(size_t)(base + j) * 48]);
                float fB = __bfloat162float(xB[(size_t)(base + j) * 48]);
                xpk[b][j] = ucast(__builtin_amdgcn_cvt_pkrtz(fA, fB));
            }
            float wfA = wact ? wbA[il * HW_ + base + jl] : 0.0f;
            float wfB = wact ? wbA[il * HW_ + W_ + base + jl] : 0.0f;
            wAr[b] = ucast(__builtin_amdgcn_cvt_pkrtz(wfA, wfB));
        }
        unsigned Au = xpk[0][7];
        #pragma unroll
        for (int cc2 = 0; cc2 < 26; ++cc2) {
            const int cc = 25 - cc2;
            const int buf = cc2 % 3;
            if (cc2 < 24) {               // prefetch 2 chunks ahead (descending)
                const int nb = (cc2 + 2) % 3;
                #pragma unroll
                for (int j = 0; j < 8; ++j) {
                    float fA = __bfloat162float(xA[(size_t)((cc - 2) * 8 + j) * 48]);
                    float fB = __bfloat162float(xB[(size_t)((cc - 2) * 8 + j) * 48]);
                    xpk[nb][j] = ucast(__builtin_amdgcn_cvt_pkrtz(fA, fB));
                }
                float wfA = wact ? wbA[il * HW_ + (cc - 2) * 8 + jl] : 0.0f;
                float wfB = wact ? wbA[il * HW_ + W_ + (cc - 2) * 8 + jl] : 0.0f;
                wAr[nb] = ucast(__builtin_amdgcn_cvt_pkrtz(wfA, wfB));
            }
            #pragma unroll
            for (int j = 7; j >= 0; --j) {
                Au = sga_step_pk(Au, xpk[buf][j], rlu(wAr[buf], j), rlu(wAr[buf], 8 + j),
                                 rlu(wAr[buf], 16 + j), rlu(wAr[buf], 24 + j),
                                 rlu(wAr[buf], 32 + j), actv, ge47);
                if (actv) sO[cc * 8 + j][d] = Au;
            }
        }
    }

    __syncthreads();

    // ---- merge: wave dir handles p in [dir*104, dir*104+104) ----
    __hip_bfloat16* dpA = d12 + ((size_t)c * HW_ + h0 * W_) * 48 + d;
    __hip_bfloat16* dpB = dpA + HS_;
    if (actv) {
        const int p0 = dir * 104;
        #pragma unroll 8
        for (int t = 0; t < 104; ++t) {
            int p = p0 + t;
            unsigned um = pkmax_u(tmpp[(size_t)p * 48], sO[p][d]);
            half2v mh = hcast(um);
            dpA[(size_t)p * 48] = __float2bfloat16((float)mh[0]);
            dpB[(size_t)p * 48] = __float2bfloat16((float)mh[1]);
        }
    }
}

// ---------------------------------------------------------------------------
// Vertical scans, PACKED fp16 column-pairs + fwd/rev split (round-11 proven).
// ---------------------------------------------------------------------------
__global__ __launch_bounds__(128, 3) void sga_h_kernel(
    const __hip_bfloat16* __restrict__ xt, const float* __restrict__ wnT,
    __hip_bfloat16* __restrict__ d12,
    const float* __restrict__ g1, const float* __restrict__ b1,
    const float* __restrict__ m1, const float* __restrict__ v1)
{
    __shared__ unsigned sO[2][64][48];    // [dir][h][d] packed {colA,colB}

    int lane = threadIdx.x & 63;
    int dir  = threadIdx.x >> 6;          // 0 = fwd (d3), 1 = rev (d4)
    int gp   = blockIdx.x;                // 0..3327 column pair
    int g0 = gp * 2;
    int c = g0 / W_, w = g0 % W_;         // colB = w+1, same c (W even)
    int d = lane < 48 ? lane : 47;
    bool actv = lane < 48, ge47 = lane >= 47;
    const __hip_bfloat16* xA = xt + ((size_t)c * HW_ + w) * 48 + d;   // + h*HS_
    const __hip_bfloat16* xB = xA + 48;
    const float* wbA = wnT + ((size_t)(dir * 5) * W_ + w) * H_;       // + i*HW_ + h
    const float* wbB = wbA + H_;
    int il = lane >> 3, jl = lane & 7;    // weight gather lane layout
    bool wact = il < 5;

    unsigned xpk[3][8];
    unsigned wAr[3];

    if (dir == 0) {
        // ---- forward scan h = 0..63 ----
        #pragma unroll
        for (int b = 0; b < 2; ++b) {
            #pragma unroll
            for (int j = 0; j < 8; ++j) {
                float fA = __bfloat162float(xA[(size_t)(b * 8 + j) * HS_]);
                float fB = __bfloat162float(xB[(size_t)(b * 8 + j) * HS_]);
                xpk[b][j] = ucast(__builtin_amdgcn_cvt_pkrtz(fA, fB));
            }
            float wfA = wact ? wbA[il * HW_ + b * 8 + jl] : 0.0f;
            float wfB = wact ? wbB[il * HW_ + b * 8 + jl] : 0.0f;
            wAr[b] = ucast(__builtin_amdgcn_cvt_pkrtz(wfA, wfB));
        }
        unsigned Au = xpk[0][0];
        #pragma unroll
        for (int cc = 0; cc < 8; ++cc) {
            const int buf = cc % 3;
            if (cc < 6) {                 // prefetch 2 chunks ahead
                const int nb = (cc + 2) % 3;
                #pragma unroll
                for (int j = 0; j < 8; ++j) {
                    float fA = __bfloat162float(xA[(size_t)((cc + 2) * 8 + j) * HS_]);
                    float fB = __bfloat162float(xB[(size_t)((cc + 2) * 8 + j) * HS_]);
                    xpk[nb][j] = ucast(__builtin_amdgcn_cvt_pkrtz(fA, fB));
                }
                float wfA = wact ? wbA[il * HW_ + (cc + 2) * 8 + jl] : 0.0f;
                float wfB = wact ? wbB[il * HW_ + (cc + 2) * 8 + jl] : 0.0f;
                wAr[nb] = ucast(__builtin_amdgcn_cvt_pkrtz(wfA, wfB));
            }
            #pragma unroll
            for (int j = 0; j < 8; ++j) {
                Au = sga_step_pk(Au, xpk[buf][j], rlu(wAr[buf], j), rlu(wAr[buf], 8 + j),
                                 rlu(wAr[buf], 16 + j), rlu(wAr[buf], 24 + j),
                                 rlu(wAr[buf], 32 + j), actv, ge47);
                if (actv) sO[0][cc * 8 + j][d] = Au;
            }
        }
    } else {
        // ---- reverse scan h = 63..0 ----
        #pragma unroll
        for (int b = 0; b < 2; ++b) {
            const int base = 56 - b * 8;
            #pragma unroll
            for (int j = 0; j < 8; ++j) {
                float fA = __bfloat162float(xA[(size_t)(base + j) * HS_]);
                float fB = __bfloat162float(xB[(size_t)(base + j) * HS_]);
                xpk[b][j] = ucast(__builtin_amdgcn_cvt_pkrtz(fA, fB));
            }
            float wfA = wact ? wbA[il * HW_ + base + jl] : 0.0f;
            float wfB = wact ? wbB[il * HW_ + base + jl] : 0.0f;
            wAr[b] = ucast(__builtin_amdgcn_cvt_pkrtz(wfA, wfB));
        }
        unsigned Au = xpk[0][7];
        #pragma unroll
        for (int cc2 = 0; cc2 < 8; ++cc2) {
            const int cc = 7 - cc2;       // chunk base descending
            const int buf = cc2 % 3;
            if (cc2 < 6) {
                const int nb = (cc2 + 2) % 3;
                #pragma unroll
                for (int j = 0; j < 8; ++j) {
                    float fA = __bfloat162float(xA[(size_t)((cc - 2) * 8 + j) * HS_]);
                    float fB = __bfloat162float(xB[(size_t)((cc - 2) * 8 + j) * HS_]);
                    xpk[nb][j] = ucast(__builtin_amdgcn_cvt_pkrtz(fA, fB));
                }
                float wfA = wact ? wbA[il * HW_ + (cc - 2) * 8 + jl] : 0.0f;
                float wfB = wact ? wbB[il * HW_ + (cc - 2) * 8 + jl] : 0.0f;
                wAr[nb] = ucast(__builtin_amdgcn_cvt_pkrtz(wfA, wfB));
            }
            #pragma unroll
            for (int j = 7; j >= 0; --j) {
                Au = sga_step_pk(Au, xpk[buf][j], rlu(wAr[buf], j), rlu(wAr[buf], 8 + j),
                                 rlu(wAr[buf], 16 + j), rlu(wAr[buf], 24 + j),
                                 rlu(wAr[buf], 32 + j), actv, ge47);
                if (actv) sO[1][cc * 8 + j][d] = Au;
            }
        }
    }

    __syncthreads();

    // ---- merge: this wave handles h in [dir*32, dir*32+32), both columns ----
    float s1 = g1[c] * rsqrtf(v1[c] + EPS_);
    float o1 = b1[c] - m1[c] * s1;
    __hip_bfloat16* dpA = d12 + ((size_t)c * HW_ + w) * 48 + d;
    __hip_bfloat16* dpB = dpA + 48;
    #pragma unroll
    for (int t = 0; t < 32; ++t) {
        int h = dir * 32 + t;
        unsigned um = pkmax_u(sO[0][h][d], sO[1][h][d]);
        half2v mh = hcast(um);
        if (actv) {
            float vA = fmaxf((float)mh[0], __bfloat162float(dpA[(size_t)h * HS_]));
            float vB = fmaxf((float)mh[1], __bfloat162float(dpB[(size_t)h * HS_]));
            dpA[(size_t)h * HS_] = __float2bfloat16(fmaxf(vA * s1 + o1, 0.0f));
            dpB[(size_t)h * HS_] = __float2bfloat16(fmaxf(vB * s1 + o1, 0.0f));
        }
    }
}

// ---------------------------------------------------------------------------
// trans: st bf16 [c][h][w][d] -> act bf16 [h][DP][WP][c], d,w shifted +1
// ---------------------------------------------------------------------------
__global__ __launch_bounds__(256) void trans_kernel(
    const __hip_bfloat16* __restrict__ st, __hip_bfloat16* __restrict__ act)
{
    __shared__ float t[8 * 1571];   // addr = wl*1571 + c*49 + d
    int tid = threadIdx.x;
    int h  = blockIdx.x / 26;
    int w0 = (blockIdx.x % 26) * 8;
    const unsigned* stu = (const unsigned*)st;
    #pragma unroll
    for (int k = 0; k < 24; ++k) {
        int f = tid + 256 * k;              // < 6144
        int d2 = f % 24, wl = (f / 24) % 8, c = f / 192;
        unsigned u = stu[(((size_t)c * HW_ + h * W_ + w0 + wl) * 48 + 2 * d2) >> 1];
        const __hip_bfloat16* bp = (const __hip_bfloat16*)&u;
        t[wl * 1571 + c * 49 + 2 * d2]     = __bfloat162float(bp[0]);
        t[wl * 1571 + c * 49 + 2 * d2 + 1] = __bfloat162float(bp[1]);
    }
    __syncthreads();
    unsigned* actu = (unsigned*)act;
    #pragma unroll
    for (int k = 0; k < 24; ++k) {
        int f = tid + 256 * k;              // < 6144
        int cp = f % 16, wl = (f / 16) % 8, d = f / 128;
        union { unsigned u; __hip_bfloat16 hh[2]; } pk;
        pk.hh[0] = __float2bfloat16(t[wl * 1571 + (2 * cp) * 49 + d]);
        pk.hh[1] = __float2bfloat16(t[wl * 1571 + (2 * cp + 1) * 49 + d]);
        actu[(((size_t)h * DP_ + d + 1) * WP_ + w0 + wl + 1) * 16 + cp] = pk.u;
    }
}

// ---------------------------------------------------------------------------
// Conv 3x3x3, block-cooperative LDS-staged implicit GEMM (MFMA 32x32x16).
// Block = 4 waves = 32co x 32w x 8d. Per kh-row: stage act brick
// [10 dp][34 wl][32 c] (c padded to 40 in LDS for bank spread) once, then
// each wave (2 d-planes, 32 AGPR acc) streams ds_read_b128 + MFMA.
// act is d- AND w-zero-padded -> no boundary logic anywhere.
// ---------------------------------------------------------------------------
__global__ __launch_bounds__(256, 4) void conv_kernel(
    const __hip_bfloat16* __restrict__ act,   // [H][DP][WP][C]
    const short8* __restrict__ wrep,          // [27][2][64] short8
    const float* __restrict__ x,
    const float* __restrict__ g2, const float* __restrict__ b2,
    const float* __restrict__ m2, const float* __restrict__ v2,
    float* __restrict__ out)
{
    __shared__ __hip_bfloat16 sAct[10 * 34 * 40];

    int tid  = threadIdx.x;
    int lane = tid & 63;
    int v    = tid >> 6;                 // wave 0..3
    int bid  = blockIdx.x;
    int wt   = bid % 7;
    int t    = bid / 7;
    int h    = t & 63;
    int d0b  = (t >> 6) * 8;             // block d-base: 0,8,...,40
    int w0   = wt * 32;
    int n    = lane & 31;
    int half = lane >> 5;

    float16v acc0 = (float16v)(0.0f);
    float16v acc1 = (float16v)(0.0f);

    const short8* ap8 = (const short8*)act;

    #pragma unroll
    for (int kh = 0; kh < 3; ++kh) {
        int hh = h + kh - 1;
        if (hh < 0 || hh >= H_) continue;          // block-uniform
        __syncthreads();                           // prev-iter reads done
        #pragma unroll
        for (int k = 0; k < 6; ++k) {
            int i = tid + 256 * k;                 // 1360 chunks of 16B
            if (i < 1360) {
                int dp = i / 136;
                int r  = i - dp * 136;
                int wl = r >> 2, q = r & 3;
                int wc = w0 + wl; wc = wc < 209 ? wc : 209;   // clamp to zero col
                short8 vd = ap8[(((size_t)hh * DP_ + d0b + dp) * WP_ + wc) * 4 + q];
                *(short8*)&sAct[(dp * 34 + wl) * 40 + q * 8] = vd;
            }
        }
        __syncthreads();
        #pragma unroll
        for (int kw = 0; kw < 3; ++kw) {
            #pragma unroll
            for (int cih = 0; cih < 2; ++cih) {
                short8 af[3];
                #pragma unroll
                for (int kd = 0; kd < 3; ++kd)
                    af[kd] = wrep[(((kd*3 + kh)*3 + kw)*2 + cih)*64 + lane];
                short8 bf[4];
                #pragma unroll
                for (int p = 0; p < 4; ++p)
                    bf[p] = *(const short8*)
                        &sAct[((2*v + p) * 34 + kw + n) * 40 + cih * 16 + half * 8];
                #pragma unroll
                for (int kd = 0; kd < 3; ++kd) {
                    acc0 = __builtin_amdgcn_mfma_f32_32x32x16_bf16(af[kd], bf[kd],   acc0, 0, 0, 0);
                    acc1 = __builtin_amdgcn_mfma_f32_32x32x16_bf16(af[kd], bf[kd+1], acc1, 0, 0, 0);
                }
            }
        }
    }

    int d0 = d0b + 2 * v;
    int wl = w0 + n;
    bool wvalid = wl < W_;
    int coh = 4 * half;
    #pragma unroll
    for (int r = 0; r < 16; ++r) {
        int co = (r & 3) + 8 * (r >> 2) + coh;
        float s2 = g2[co] * rsqrtf(v2[co] + EPS_);
        float o2 = b2[co] - m2[co] * s2;
        size_t idx0 = ((size_t)(co * D_ + d0) * H_ + h) * W_ + wl;
        if (wvalid) {
            out[idx0]       = fmaxf(acc0[r] * s2 + o2 + x[idx0],       0.0f);
            out[idx0 + HW_] = fmaxf(acc1[r] * s2 + o2 + x[idx0 + HW_], 0.0f);
        }
    }
}

// ---------------------------------------------------------------------------
extern "C" void kernel_launch(void* const* d_in, const int* in_sizes, int n_in,
                              void* d_out, int out_size, void* d_ws, size_t ws_size,
                              hipStream_t stream)
{
    const float* x    = (const float*)d_in[0];
    const float* g    = (const float*)d_in[1];
    const float* cw   = (const float*)d_in[2];
    const float* bn1g = (const float*)d_in[3];
    const float* bn1b = (const float*)d_in[4];
    const float* bn1m = (const float*)d_in[5];
    const float* bn1v = (const float*)d_in[6];
    const float* bn2g = (const float*)d_in[7];
    const float* bn2b = (const float*)d_in[8];
    const float* bn2m = (const float*)d_in[9];
    const float* bn2v = (const float*)d_in[10];
    float* out = (float*)d_out;

    char* ws = (char*)d_ws;
    float* wn  = (float*)ws;                                   // 1,064,960 B
    float* wnT = (float*)(ws + 1064960);                       //   532,480 B
    __hip_bfloat16* wrep = (__hip_bfloat16*)(ws + 1597440);    //    55,296 B
    __hip_bfloat16* d12t = (__hip_bfloat16*)(ws + 1652736);    // 40,894,464 B
    __hip_bfloat16* act  = (__hip_bfloat16*)(ws + 42547200);   // 43,008,000 B (d+w padded)
    __hip_bfloat16* xt = (__hip_bfloat16*)out;  // d_out bytes [0, 40894464): bf16 xt scratch
    unsigned* d1tmp = (unsigned*)((char*)out + 40894464);      // d_out second half: 40,894,464 B

    prep_kernel<<<2380, 256, 0, stream>>>(g, cw, wn, wnT, wrep, (unsigned*)act);
    t0_kernel<<<1664, 256, 0, stream>>>(x, xt);
    sga_w_kernel<<<1024, 128, 0, stream>>>(xt, wn, d12t, d1tmp);
    sga_h_kernel<<<3328, 128, 0, stream>>>(xt, wnT, d12t, bn1g, bn1b, bn1m, bn1v);
    trans_kernel<<<1664, 256, 0, stream>>>(d12t, act);
    conv_kernel<<<2688, 256, 0, stream>>>(act, (const short8*)wrep, x,
                                          bn2g, bn2b, bn2m, bn2v, out);
}